// Round 4
// baseline (1149.582 us; speedup 1.0000x reference)
//
#include <hip/hip_runtime.h>

#define NB 4
#define NN 50000

// ---- workspace byte offsets (total ~205.15 MB, < proven 205.9 MB) ----
#define H0B   0L
#define H1B   51200000L
#define VTB   102400000L     // v (GLU out, bf16); start doubles as RM (fp32) before GLU0
#define RMB   102400000L
#define QB    153600000L
#define KKB   179200000L
#define WBFB  204800000L     // bf16 GLU weights: layer0 [256][128], layer1 at +65536B
#define V2FB  204931072L     // fp32 v2x [4][64][128]
#define V2TB  205062144L     // bf16 v2x^T+ksum [4][144][64]
#define KSB   205135872L     // fp32 ksum [4][64]
#define GMB   205136896L     // 4 uints
#define PJB   205137920L     // fp32 projT [32][64]

typedef short short8_t __attribute__((ext_vector_type(8)));
typedef float f32x4 __attribute__((ext_vector_type(4)));

__device__ __forceinline__ unsigned short f2bf(float f){
  unsigned u = __float_as_uint(f);
  return (unsigned short)((u + 0x7FFFu + ((u>>16)&1u)) >> 16);
}
__device__ __forceinline__ float bf2f(unsigned short s){
  return __uint_as_float(((unsigned)s)<<16);
}
__device__ __forceinline__ unsigned pk2(float a, float b){
  return (unsigned)f2bf(a) | ((unsigned)f2bf(b)<<16);
}
__device__ __forceinline__ uint4 pk8(const float* f){
  uint4 o; o.x=pk2(f[0],f[1]); o.y=pk2(f[2],f[3]);
  o.z=pk2(f[4],f[5]); o.w=pk2(f[6],f[7]); return o;
}
__device__ __forceinline__ void up8(uint4 v, float* f){
  f[0]=bf2f((unsigned short)(v.x&0xFFFFu)); f[1]=bf2f((unsigned short)(v.x>>16));
  f[2]=bf2f((unsigned short)(v.y&0xFFFFu)); f[3]=bf2f((unsigned short)(v.y>>16));
  f[4]=bf2f((unsigned short)(v.z&0xFFFFu)); f[5]=bf2f((unsigned short)(v.z>>16));
  f[6]=bf2f((unsigned short)(v.w&0xFFFFu)); f[7]=bf2f((unsigned short)(v.w>>16));
}
__device__ __forceinline__ unsigned encOrd(float f){
  unsigned u = __float_as_uint(f);
  return (u & 0x80000000u) ? ~u : (u | 0x80000000u);
}
__device__ __forceinline__ float decOrd(unsigned u){
  return (u & 0x80000000u) ? __uint_as_float(u & 0x7fffffffu)
                           : __uint_as_float(~u);
}
__device__ __forceinline__ uint2 mku2(unsigned a, unsigned b){ uint2 t; t.x=a; t.y=b; return t; }

// ---- zero ksum + gmax ----
__global__ void k_init0(char* __restrict__ wsb){
  int t = threadIdx.x;
  ((float*)(wsb + KSB))[t] = 0.0f;
  if (t < 4) ((unsigned*)(wsb + GMB))[t] = 0u;
}
// ---- zero v2x fp32 ----
__global__ void k_initv2(char* __restrict__ wsb){
  int i = blockIdx.x*256 + threadIdx.x;
  if (i < 32768) ((float*)(wsb + V2FB))[i] = 0.0f;
}
// ---- GLU weights -> bf16 [n][k] ----
__global__ void k_wcvt(const float* __restrict__ wi0, const float* __restrict__ wo0,
                       const float* __restrict__ wi1, const float* __restrict__ wo1,
                       char* __restrict__ wsb){
  int idx = blockIdx.x*256 + threadIdx.x;
  if (idx >= 65536) return;
  int l = idx >> 15, r = (idx >> 7) & 255, c = idx & 127;
  const float* src = (l==0) ? ((r<128)? wi0 : wo0) : ((r<128)? wi1 : wo1);
  float v = src[(r&127)*128 + c];
  ((unsigned short*)(wsb + WBFB))[l*32768 + r*128 + c] = f2bf(v);
}
// ---- projT[j][m] = proj[m][j], fp32 ----
__global__ void k_pjcvt(const float* __restrict__ proj, char* __restrict__ wsb){
  int idx = blockIdx.x*256 + threadIdx.x;      // 2048
  if (idx >= 2048) return;
  int j = idx >> 6, m = idx & 63;
  ((float*)(wsb + PJB))[j*64 + m] = proj[m*32 + j];
}

// ---------- pass1 (phase-split): h0, q, k', rm, global key max -------------
__global__ __launch_bounds__(256) void k_pass1(
  const float* __restrict__ x, const float* __restrict__ node_emb,
  const float* __restrict__ time_emb, const float* __restrict__ week_emb,
  const float* __restrict__ W_in, const float* __restrict__ b_in,
  const float* __restrict__ W1, const float* __restrict__ b1,
  const float* __restrict__ W2, const float* __restrict__ b2,
  char* __restrict__ wsb)
{
  const int b = blockIdx.y;
  const int n = blockIdx.x*256 + threadIdx.x;
  const bool act = (n < NN);
  float kmx = -3.0e38f;
  if (act) {
    const long row = (long)b*NN + n;
    // ---- phase A: inp + embeddings ----
    float xg[96];
    uint4* h0q = (uint4*)(wsb + H0B) + row*16;
    {
      float xr[36];
      const float4* xp = (const float4*)(x + row*36);
      #pragma unroll
      for (int i=0;i<9;i++){ float4 t=xp[i]; xr[4*i]=t.x; xr[4*i+1]=t.y; xr[4*i+2]=t.z; xr[4*i+3]=t.w; }
      int tidx = (int)(xr[34]*288.0f); tidx = tidx<0?0:(tidx>287?287:tidx);
      int widx = (int)(xr[35]);        widx = widx<0?0:(widx>6?6:widx);
      float hh[32];
      #pragma unroll 1
      for (int jj=0;jj<8;jj++){
        #pragma unroll
        for (int jl=0;jl<4;jl++){
          const int j = jj*4+jl;
          const float* w = W_in + j*36;
          float a0=0.f,a1=0.f,a2=0.f,a3=0.f;
          #pragma unroll
          for (int i=0;i<36;i+=4){ a0+=xr[i]*w[i]; a1+=xr[i+1]*w[i+1]; a2+=xr[i+2]*w[i+2]; a3+=xr[i+3]*w[i+3]; }
          hh[j] = b_in[j] + ((a0+a1)+(a2+a3));
        }
      }
      #pragma unroll
      for (int c=0;c<4;c++) h0q[c] = pk8(hh + 8*c);
      const float4* p0 = (const float4*)(node_emb + (long)n*32);
      const float4* p1 = (const float4*)(time_emb + (long)tidx*32);
      const float4* p2 = (const float4*)(week_emb + (long)widx*32);
      #pragma unroll
      for (int i=0;i<8;i++){ float4 t=p0[i]; xg[4*i]=t.x; xg[4*i+1]=t.y; xg[4*i+2]=t.z; xg[4*i+3]=t.w; }
      #pragma unroll
      for (int i=0;i<8;i++){ float4 t=p1[i]; xg[32+4*i]=t.x; xg[32+4*i+1]=t.y; xg[32+4*i+2]=t.z; xg[32+4*i+3]=t.w; }
      #pragma unroll
      for (int i=0;i<8;i++){ float4 t=p2[i]; xg[64+4*i]=t.x; xg[64+4*i+1]=t.y; xg[64+4*i+2]=t.z; xg[64+4*i+3]=t.w; }
      #pragma unroll
      for (int c=0;c<12;c++) h0q[4+c] = pk8(xg + 8*c);
    }
    // ---- phase B: d1 = (xg@W1^T+b1)*DSC, d2 = (xg@W2^T+b2)*DSC ----
    const float DSC = 0.42044820762685725f;   // 32^-0.25
    float d1[32], d2[32];
    #pragma unroll 1
    for (int j=0;j<32;j++){
      const float* w1r = W1 + j*96;
      const float* w2r = W2 + j*96;
      float a0=0.f,a1=0.f,a2=0.f,a3=0.f,c0=0.f,c1=0.f,c2=0.f,c3=0.f;
      #pragma unroll
      for (int i=0;i<96;i+=4){
        a0+=xg[i]*w1r[i]; a1+=xg[i+1]*w1r[i+1]; a2+=xg[i+2]*w1r[i+2]; a3+=xg[i+3]*w1r[i+3];
        c0+=xg[i]*w2r[i]; c1+=xg[i+1]*w2r[i+1]; c2+=xg[i+2]*w2r[i+2]; c3+=xg[i+3]*w2r[i+3];
      }
      d1[j] = (b1[j] + ((a0+a1)+(a2+a3))) * DSC;
      d2[j] = (b2[j] + ((c0+c1)+(c2+c3))) * DSC;
    }
    const float* projT = (const float*)(wsb + PJB);
    // ---- phase C: q side ----
    {
      float dash[64];
      #pragma unroll
      for (int m=0;m<64;m++) dash[m]=0.f;
      float diag = 0.f;
      #pragma unroll 1
      for (int j=0;j<32;j++){
        float dj = d1[j]; diag += dj*dj;
        const float* pj = projT + j*64;
        #pragma unroll
        for (int m=0;m<64;m++) dash[m] += dj * pj[m];
      }
      diag *= 0.5f;
      float mx = dash[0];
      #pragma unroll
      for (int m=1;m<64;m++) mx = fmaxf(mx, dash[m]);
      uint4* qq = (uint4*)(wsb + QB) + row*8;
      #pragma unroll
      for (int mm=0;mm<8;mm++){
        float t[8];
        #pragma unroll
        for (int e=0;e<8;e++) t[e] = 0.125f*(__expf(dash[8*mm+e]-diag-mx)+1e-6f);
        qq[mm] = pk8(t);
      }
    }
    // ---- phase D: k side ----
    {
      float dash[64];
      #pragma unroll
      for (int m=0;m<64;m++) dash[m]=0.f;
      float diag = 0.f;
      #pragma unroll 1
      for (int j=0;j<32;j++){
        float dj = d2[j]; diag += dj*dj;
        const float* pj = projT + j*64;
        #pragma unroll
        for (int m=0;m<64;m++) dash[m] += dj * pj[m];
      }
      diag *= 0.5f;
      kmx = dash[0];
      #pragma unroll
      for (int m=1;m<64;m++) kmx = fmaxf(kmx, dash[m]);
      uint4* kq = (uint4*)(wsb + KKB) + row*8;
      #pragma unroll
      for (int mm=0;mm<8;mm++){
        float t[8];
        #pragma unroll
        for (int e=0;e<8;e++) t[e] = __expf(dash[8*mm+e]-kmx);   // k' in (0,1]
        kq[mm] = pk8(t);
      }
      ((float*)(wsb + RMB))[row] = kmx - diag;
    }
  }
  #pragma unroll
  for (int off=32; off>0; off>>=1) kmx = fmaxf(kmx, __shfl_xor(kmx, off));
  __shared__ float wred[4];
  if ((threadIdx.x & 63)==0) wred[threadIdx.x>>6] = kmx;
  __syncthreads();
  if (threadIdx.x==0){
    float m2 = fmaxf(fmaxf(wred[0],wred[1]), fmaxf(wred[2],wred[3]));
    atomicMax((unsigned*)(wsb + GMB) + b, encOrd(m2));
  }
}

// ---------- finalize k = 0.125*(k'*exp(rm-gmax)+1e-6) ----------------------
__global__ __launch_bounds__(256) void k_kfin(char* __restrict__ wsb){
  const int b = blockIdx.y;
  const int n = blockIdx.x*256 + threadIdx.x;
  if (n >= NN) return;
  const long row = (long)b*NN + n;
  const float gm = decOrd(((const unsigned*)(wsb + GMB))[b]);
  const float scale = __expf(((const float*)(wsb + RMB))[row] - gm);
  uint4* kq = (uint4*)(wsb + KKB) + row*8;
  #pragma unroll
  for (int mm=0;mm<8;mm++){
    float t[8]; up8(kq[mm], t);
    #pragma unroll
    for (int e=0;e<8;e++) t[e] = 0.125f*(t[e]*scale + 1e-6f);
    kq[mm] = pk8(t);
  }
}

// ---------- MFMA GLU with LDS-staged output --------------------------------
__global__ __launch_bounds__(256) void k_glu(
  const unsigned short* __restrict__ h, const unsigned short* __restrict__ wbf,
  const float* __restrict__ bi, const float* __restrict__ bo,
  unsigned short* __restrict__ vout)
{
  __shared__ unsigned short vt[64][132];
  const int tid = threadIdx.x;
  const int lane = tid & 63;
  const int wid  = tid >> 6;
  const int c  = lane & 15;
  const int kg = lane >> 4;
  const long r0blk = (long)blockIdx.x*64;           // 3125*64 = 200000 exact
  const unsigned short* arow = h + (r0blk + wid*16 + c)*128 + kg*8;
  f32x4 acc[16];
  #pragma unroll
  for (int f=0;f<16;f++) acc[f] = (f32x4){0.f,0.f,0.f,0.f};
  #pragma unroll
  for (int ks=0;ks<4;ks++){
    short8_t a = *(const short8_t*)(arow + ks*32);
    #pragma unroll
    for (int f=0;f<16;f++){
      short8_t bb = *(const short8_t*)(wbf + (f*16 + c)*128 + ks*32 + kg*8);
      acc[f] = __builtin_amdgcn_mfma_f32_16x16x32_bf16(a, bb, acc[f], 0, 0, 0);
    }
  }
  float bi_l[8], bo_l[8];
  #pragma unroll
  for (int f=0;f<8;f++){ bi_l[f] = bi[f*16+c]; bo_l[f] = bo[f*16+c]; }
  #pragma unroll
  for (int f=0;f<8;f++){
    #pragma unroll
    for (int j=0;j<4;j++){
      float a  = acc[f][j]   + bi_l[f];
      float cc = acc[f+8][j] + bo_l[f];
      float o  = cc / (1.0f + __expf(-a));
      vt[wid*16 + kg*4 + j][f*16 + c] = f2bf(o);
    }
  }
  __syncthreads();
  {
    int row = tid>>2, q = tid&3;
    const uint2* s = (const uint2*)&vt[row][q*32];
    uint2 a0=s[0],a1=s[1],a2=s[2],a3=s[3],a4=s[4],a5=s[5],a6=s[6],a7=s[7];
    uint4* dst = (uint4*)(vout + (r0blk + row)*128 + q*32);
    uint4 o0; o0.x=a0.x; o0.y=a0.y; o0.z=a1.x; o0.w=a1.y;
    uint4 o1; o1.x=a2.x; o1.y=a2.y; o1.z=a3.x; o1.w=a3.y;
    uint4 o2; o2.x=a4.x; o2.y=a4.y; o2.z=a5.x; o2.w=a5.y;
    uint4 o3; o3.x=a6.x; o3.y=a6.y; o3.z=a7.x; o3.w=a7.y;
    dst[0]=o0; dst[1]=o1; dst[2]=o2; dst[3]=o3;
  }
}

// ---------- ksum ------------------------------------------------------------
__global__ __launch_bounds__(256) void k_ksum(char* __restrict__ wsb){
  const int b = blockIdx.y;
  const int r0 = blockIdx.x*512;
  const int m2 = threadIdx.x & 31;
  const int rq = threadIdx.x >> 5;
  const int rend = min(r0+512, NN);
  const unsigned* kk = (const unsigned*)(wsb + KKB) + (long)b*NN*32;
  float a0=0.f, a1=0.f;
  for (int r=r0+rq; r<rend; r+=8){
    unsigned u = kk[(long)r*32 + m2];
    a0 += bf2f((unsigned short)(u&0xFFFFu));
    a1 += bf2f((unsigned short)(u>>16));
  }
  __shared__ float red0[8][32], red1[8][32];
  red0[rq][m2]=a0; red1[rq][m2]=a1;
  __syncthreads();
  if (threadIdx.x < 32){
    float s0=0.f, s1=0.f;
    #pragma unroll
    for (int q=0;q<8;q++){ s0+=red0[q][threadIdx.x]; s1+=red1[q][threadIdx.x]; }
    float* ks = (float*)(wsb + KSB) + b*64;
    atomicAdd(ks + 2*threadIdx.x,     s0);
    atomicAdd(ks + 2*threadIdx.x + 1, s1);
  }
}

// ---------- v2x[b][m][d] = sum_n k[n][m]*v[n][d] ---------------------------
__global__ __launch_bounds__(256) void k_reduce(const char* __restrict__ wsb,
                                                const unsigned short* __restrict__ vt,
                                                float* __restrict__ v2x)
{
  const int b  = blockIdx.y;
  const int r0 = blockIdx.x*512;
  __shared__ unsigned short klds[64*64];
  __shared__ unsigned short vlds[64*128];
  const int tid = threadIdx.x;
  const int mg = tid >> 4;
  const int dg = tid & 15;
  float acc[4][8];
  #pragma unroll
  for (int f=0;f<4;f++)
    #pragma unroll
    for (int e=0;e<8;e++) acc[f][e]=0.f;
  const uint4* kbase = (const uint4*)(wsb + KKB) + (long)b*NN*8;
  const uint4* vbase = (const uint4*)vt + (long)b*NN*16;
  const int rend = min(r0+512, NN);
  for (int t0=r0; t0<rend; t0+=64){
    __syncthreads();
    #pragma unroll
    for (int e=0;e<2;e++){
      int f = tid + 256*e;
      int rr = f >> 3, cc = f & 7;
      int gr = t0 + rr;
      uint4 val = {0u,0u,0u,0u};
      if (gr < NN) val = kbase[(long)gr*8 + cc];
      ((uint4*)klds)[f] = val;
    }
    #pragma unroll
    for (int e=0;e<4;e++){
      int f = tid + 256*e;
      int rr = f >> 4, cc = f & 15;
      int gr = t0 + rr;
      uint4 val = {0u,0u,0u,0u};
      if (gr < NN) val = vbase[(long)gr*16 + cc];
      ((uint4*)vlds)[f] = val;
    }
    __syncthreads();
    #pragma unroll 2
    for (int r=0;r<64;r++){
      uint2 kv = ((const uint2*)klds)[r*16 + mg];
      uint4 vv = ((const uint4*)vlds)[r*16 + dg];
      float kkv[4] = { bf2f((unsigned short)(kv.x&0xFFFFu)), bf2f((unsigned short)(kv.x>>16)),
                       bf2f((unsigned short)(kv.y&0xFFFFu)), bf2f((unsigned short)(kv.y>>16)) };
      float vvv[8]; up8(vv, vvv);
      #pragma unroll
      for (int f=0;f<4;f++)
        #pragma unroll
        for (int e=0;e<8;e++) acc[f][e] += kkv[f]*vvv[e];
    }
  }
  #pragma unroll
  for (int f=0;f<4;f++)
    #pragma unroll
    for (int e=0;e<8;e++)
      atomicAdd(&v2x[(long)b*8192 + (mg*4+f)*128 + dg*8+e], acc[f][e]);
}

// ---------- v2t[b][n][m]: n<128: v2x[m][n]; n=128: ksum[m]; n>128: 0 -------
__global__ void k_v2cvt(char* __restrict__ wsb){
  int idx = blockIdx.x*256 + threadIdx.x;          // 36864
  if (idx >= 36864) return;
  int b = idx / 9216, rem = idx % 9216;
  int n = rem / 64, m = rem % 64;
  const float* v2f = (const float*)(wsb + V2FB);
  const float* ks  = (const float*)(wsb + KSB);
  float v = (n < 128) ? v2f[b*8192 + m*128 + n] : ((n==128) ? ks[b*64+m] : 0.f);
  ((unsigned short*)(wsb + V2TB))[b*9216 + n*64 + m] = f2bf(v);
}

// ---------- MFMA attn-apply + residual(h0,LDS) + LN -> h1 ------------------
__global__ __launch_bounds__(256) void k_attnln(
  const char* __restrict__ wsb, const float* __restrict__ g0,
  const float* __restrict__ bt0)
{
  __shared__ unsigned short ht[64][132];
  const int b = blockIdx.y;
  const int tid = threadIdx.x;
  const int lane = tid & 63;
  const int wid  = tid >> 6;
  const int c  = lane & 15;
  const int kg = lane >> 4;
  const long r0blk = (long)blockIdx.x*64;
  const unsigned short* h0g = (const unsigned short*)(wsb + H0B);
  unsigned short* h1g = (unsigned short*)(wsb + H1B);
  // stage h0 tile
  {
    int row = tid>>2, q = tid&3;
    long gr = r0blk + row;
    uint4 v0={0,0,0,0}, v1=v0, v2=v0, v3=v0;
    if (gr < NN){
      const uint4* src = (const uint4*)(h0g + ((long)b*NN + gr)*128 + q*32);
      v0=src[0]; v1=src[1]; v2=src[2]; v3=src[3];
    }
    uint2* d = (uint2*)&ht[row][q*32];
    d[0]=mku2(v0.x,v0.y); d[1]=mku2(v0.z,v0.w); d[2]=mku2(v1.x,v1.y); d[3]=mku2(v1.z,v1.w);
    d[4]=mku2(v2.x,v2.y); d[5]=mku2(v2.z,v2.w); d[6]=mku2(v3.x,v3.y); d[7]=mku2(v3.z,v3.w);
  }
  __syncthreads();
  const long r0w = r0blk + wid*16;
  const unsigned short* v2t = (const unsigned short*)(wsb + V2TB) + b*9216;
  short8_t aq[2];
  if (r0w + c < NN){
    const unsigned short* qrow = (const unsigned short*)(wsb + QB) + ((long)b*NN + r0w + c)*64 + kg*8;
    aq[0] = *(const short8_t*)(qrow);
    aq[1] = *(const short8_t*)(qrow + 32);
  } else {
    aq[0] = (short8_t){0,0,0,0,0,0,0,0};
    aq[1] = (short8_t){0,0,0,0,0,0,0,0};
  }
  f32x4 acc[9];
  #pragma unroll
  for (int f=0;f<9;f++) acc[f] = (f32x4){0.f,0.f,0.f,0.f};
  #pragma unroll
  for (int ks=0;ks<2;ks++){
    #pragma unroll
    for (int f=0;f<9;f++){
      short8_t bb = *(const short8_t*)(v2t + (f*16 + c)*64 + ks*32 + kg*8);
      acc[f] = __builtin_amdgcn_mfma_f32_16x16x32_bf16(aq[ks], bb, acc[f], 0, 0, 0);
    }
  }
  float inv[4];
  #pragma unroll
  for (int j=0;j<4;j++){
    float o2 = __shfl(acc[8][j], (lane & 48));   // col 128 = ksum dot
    inv[j] = 1.0f / o2;
  }
  float t[8][4];
  #pragma unroll
  for (int f=0;f<8;f++)
    #pragma unroll
    for (int j=0;j<4;j++)
      t[f][j] = acc[f][j]*inv[j] + bf2f(ht[wid*16 + kg*4 + j][f*16 + c]);
  float mu[4], rs[4];
  #pragma unroll
  for (int j=0;j<4;j++){
    float s = 0.f;
    #pragma unroll
    for (int f=0;f<8;f++) s += t[f][j];
    #pragma unroll
    for (int off=1; off<16; off<<=1) s += __shfl_xor(s, off);
    mu[j] = s * (1.0f/128.0f);
  }
  #pragma unroll
  for (int j=0;j<4;j++){
    float s = 0.f;
    #pragma unroll
    for (int f=0;f<8;f++){ float e = t[f][j]-mu[j]; s += e*e; }
    #pragma unroll
    for (int off=1; off<16; off<<=1) s += __shfl_xor(s, off);
    rs[j] = rsqrtf(s * (1.0f/128.0f) + 1e-5f);
  }
  float g_l[8], bt_l[8];
  #pragma unroll
  for (int f=0;f<8;f++){ g_l[f] = g0[f*16+c]; bt_l[f] = bt0[f*16+c]; }
  #pragma unroll
  for (int f=0;f<8;f++)
    #pragma unroll
    for (int j=0;j<4;j++){
      float o = (t[f][j]-mu[j])*rs[j]*g_l[f] + bt_l[f];
      ht[wid*16 + kg*4 + j][f*16 + c] = f2bf(o);   // reader==writer per element
    }
  __syncthreads();
  {
    int row = tid>>2, q = tid&3;
    long gr = r0blk + row;
    if (gr < NN){
      const uint2* s = (const uint2*)&ht[row][q*32];
      uint2 a0=s[0],a1=s[1],a2=s[2],a3=s[3],a4=s[4],a5=s[5],a6=s[6],a7=s[7];
      uint4* dst = (uint4*)(h1g + ((long)b*NN + gr)*128 + q*32);
      uint4 o0; o0.x=a0.x; o0.y=a0.y; o0.z=a1.x; o0.w=a1.y;
      uint4 o1; o1.x=a2.x; o1.y=a2.y; o1.z=a3.x; o1.w=a3.y;
      uint4 o2; o2.x=a4.x; o2.y=a4.y; o2.z=a5.x; o2.w=a5.y;
      uint4 o3; o3.x=a6.x; o3.y=a6.y; o3.z=a7.x; o3.w=a7.y;
      dst[0]=o0; dst[1]=o1; dst[2]=o2; dst[3]=o3;
    }
  }
}

// ---------- MFMA attn-apply + residual(h1) + LN1 + regression head ---------
__global__ __launch_bounds__(256) void k_attnhead(
  const char* __restrict__ wsb, const float* __restrict__ g1,
  const float* __restrict__ bt1, const float* __restrict__ W_reg,
  const float* __restrict__ b_reg, float* __restrict__ out)
{
  __shared__ unsigned short ht[64][132];
  const int b = blockIdx.y;
  const int tid = threadIdx.x;
  const int lane = tid & 63;
  const int wid  = tid >> 6;
  const int c  = lane & 15;
  const int kg = lane >> 4;
  const long r0blk = (long)blockIdx.x*64;
  const unsigned short* h0g = (const unsigned short*)(wsb + H0B);
  const unsigned short* h1g = (const unsigned short*)(wsb + H1B);
  // stage h1 tile
  {
    int row = tid>>2, q = tid&3;
    long gr = r0blk + row;
    uint4 v0={0,0,0,0}, v1=v0, v2=v0, v3=v0;
    if (gr < NN){
      const uint4* src = (const uint4*)(h1g + ((long)b*NN + gr)*128 + q*32);
      v0=src[0]; v1=src[1]; v2=src[2]; v3=src[3];
    }
    uint2* d = (uint2*)&ht[row][q*32];
    d[0]=mku2(v0.x,v0.y); d[1]=mku2(v0.z,v0.w); d[2]=mku2(v1.x,v1.y); d[3]=mku2(v1.z,v1.w);
    d[4]=mku2(v2.x,v2.y); d[5]=mku2(v2.z,v2.w); d[6]=mku2(v3.x,v3.y); d[7]=mku2(v3.z,v3.w);
  }
  __syncthreads();
  const long r0w = r0blk + wid*16;
  const unsigned short* v2t = (const unsigned short*)(wsb + V2TB) + b*9216;
  short8_t aq[2];
  if (r0w + c < NN){
    const unsigned short* qrow = (const unsigned short*)(wsb + QB) + ((long)b*NN + r0w + c)*64 + kg*8;
    aq[0] = *(const short8_t*)(qrow);
    aq[1] = *(const short8_t*)(qrow + 32);
  } else {
    aq[0] = (short8_t){0,0,0,0,0,0,0,0};
    aq[1] = (short8_t){0,0,0,0,0,0,0,0};
  }
  f32x4 acc[9];
  #pragma unroll
  for (int f=0;f<9;f++) acc[f] = (f32x4){0.f,0.f,0.f,0.f};
  #pragma unroll
  for (int ks=0;ks<2;ks++){
    #pragma unroll
    for (int f=0;f<9;f++){
      short8_t bb = *(const short8_t*)(v2t + (f*16 + c)*64 + ks*32 + kg*8);
      acc[f] = __builtin_amdgcn_mfma_f32_16x16x32_bf16(aq[ks], bb, acc[f], 0, 0, 0);
    }
  }
  float inv[4];
  #pragma unroll
  for (int j=0;j<4;j++){
    float o2 = __shfl(acc[8][j], (lane & 48));
    inv[j] = 1.0f / o2;
  }
  float t[8][4];
  #pragma unroll
  for (int f=0;f<8;f++)
    #pragma unroll
    for (int j=0;j<4;j++)
      t[f][j] = acc[f][j]*inv[j] + bf2f(ht[wid*16 + kg*4 + j][f*16 + c]);
  float mu[4], rs[4];
  #pragma unroll
  for (int j=0;j<4;j++){
    float s = 0.f;
    #pragma unroll
    for (int f=0;f<8;f++) s += t[f][j];
    #pragma unroll
    for (int off=1; off<16; off<<=1) s += __shfl_xor(s, off);
    mu[j] = s * (1.0f/128.0f);
  }
  #pragma unroll
  for (int j=0;j<4;j++){
    float s = 0.f;
    #pragma unroll
    for (int f=0;f<8;f++){ float e = t[f][j]-mu[j]; s += e*e; }
    #pragma unroll
    for (int off=1; off<16; off<<=1) s += __shfl_xor(s, off);
    rs[j] = rsqrtf(s * (1.0f/128.0f) + 1e-5f);
  }
  float g_l[8], bt_l[8];
  #pragma unroll
  for (int f=0;f<8;f++){ g_l[f] = g1[f*16+c]; bt_l[f] = bt1[f*16+c]; }
  #pragma unroll
  for (int f=0;f<8;f++)
    #pragma unroll
    for (int j=0;j<4;j++)
      t[f][j] = fmaxf((t[f][j]-mu[j])*rs[j]*g_l[f] + bt_l[f], 0.f);   // relu(h2)
  // restage h0 tile for relu(h0) head input
  __syncthreads();
  {
    int row = tid>>2, q = tid&3;
    long gr = r0blk + row;
    uint4 v0={0,0,0,0}, v1=v0, v2=v0, v3=v0;
    if (gr < NN){
      const uint4* src = (const uint4*)(h0g + ((long)b*NN + gr)*128 + q*32);
      v0=src[0]; v1=src[1]; v2=src[2]; v3=src[3];
    }
    uint2* d = (uint2*)&ht[row][q*32];
    d[0]=mku2(v0.x,v0.y); d[1]=mku2(v0.z,v0.w); d[2]=mku2(v1.x,v1.y); d[3]=mku2(v1.z,v1.w);
    d[4]=mku2(v2.x,v2.y); d[5]=mku2(v2.z,v2.w); d[6]=mku2(v3.x,v3.y); d[7]=mku2(v3.z,v3.w);
  }
  __syncthreads();
  float y[12][4];
  #pragma unroll
  for (int tt=0;tt<12;tt++)
    #pragma unroll
    for (int j=0;j<4;j++) y[tt][j] = 0.f;
  #pragma unroll
  for (int f=0;f<8;f++){
    float u0j[4];
    #pragma unroll
    for (int j=0;j<4;j++)
      u0j[j] = fmaxf(bf2f(ht[wid*16 + kg*4 + j][f*16 + c]), 0.f);
    #pragma unroll
    for (int tt=0;tt<12;tt++){
      float wl = W_reg[tt*256 + f*16 + c];
      float wh = W_reg[tt*256 + 128 + f*16 + c];
      #pragma unroll
      for (int j=0;j<4;j++) y[tt][j] += u0j[j]*wl + t[f][j]*wh;
    }
  }
  #pragma unroll
  for (int tt=0;tt<12;tt++)
    #pragma unroll
    for (int j=0;j<4;j++){
      float s = y[tt][j];
      #pragma unroll
      for (int off=1; off<16; off<<=1) s += __shfl_xor(s, off);
      long gr = r0w + kg*4 + j;
      if (c == tt && gr < NN)
        out[((long)b*12 + tt)*NN + gr] = s + b_reg[tt];
    }
}

extern "C" void kernel_launch(void* const* d_in, const int* in_sizes, int n_in,
                              void* d_out, int out_size, void* d_ws, size_t ws_size,
                              hipStream_t stream)
{
  const float* x        = (const float*)d_in[0];
  const float* node_emb = (const float*)d_in[1];
  const float* time_emb = (const float*)d_in[2];
  const float* week_emb = (const float*)d_in[3];
  const float* W_in     = (const float*)d_in[4];
  const float* b_in     = (const float*)d_in[5];
  const float* W1       = (const float*)d_in[6];
  const float* b1       = (const float*)d_in[7];
  const float* W2       = (const float*)d_in[8];
  const float* b2       = (const float*)d_in[9];
  const float* W_reg    = (const float*)d_in[10];
  const float* b_reg    = (const float*)d_in[11];
  const float* proj     = (const float*)d_in[12];
  const float* fc_in0_w = (const float*)d_in[13];
  const float* fc_in0_b = (const float*)d_in[14];
  const float* fc_out0_w= (const float*)d_in[15];
  const float* fc_out0_b= (const float*)d_in[16];
  const float* ln0_g    = (const float*)d_in[17];
  const float* ln0_b    = (const float*)d_in[18];
  const float* fc_in1_w = (const float*)d_in[19];
  const float* fc_in1_b = (const float*)d_in[20];
  const float* fc_out1_w= (const float*)d_in[21];
  const float* fc_out1_b= (const float*)d_in[22];
  const float* ln1_g    = (const float*)d_in[23];
  const float* ln1_b    = (const float*)d_in[24];
  char* wsb  = (char*)d_ws;
  float* out = (float*)d_out;

  dim3 rowgrid((NN+255)/256, NB);     // (196, 4)
  dim3 redgrid((NN+511)/512, NB);     // (98, 4)
  dim3 glugrid(3125);                 // 3125*64 = 200000 rows
  dim3 atngrid(782, NB);              // 782*64 = 50048 >= NN

  k_init0 <<<1, 256, 0, stream>>>(wsb);
  k_wcvt  <<<256, 256, 0, stream>>>(fc_in0_w, fc_out0_w, fc_in1_w, fc_out1_w, wsb);
  k_pjcvt <<<8, 256, 0, stream>>>(proj, wsb);
  k_pass1 <<<rowgrid, 256, 0, stream>>>(x, node_emb, time_emb, week_emb,
                                        W_in, b_in, W1, b1, W2, b2, wsb);
  k_kfin  <<<rowgrid, 256, 0, stream>>>(wsb);
  k_glu   <<<glugrid, 256, 0, stream>>>((const unsigned short*)(wsb + H0B),
                                        (const unsigned short*)(wsb + WBFB),
                                        fc_in0_b, fc_out0_b,
                                        (unsigned short*)(wsb + VTB));
  k_ksum  <<<redgrid, 256, 0, stream>>>(wsb);
  k_initv2<<<128, 256, 0, stream>>>(wsb);
  k_reduce<<<redgrid, 256, 0, stream>>>(wsb, (const unsigned short*)(wsb + VTB),
                                        (float*)(wsb + V2FB));
  k_v2cvt <<<144, 256, 0, stream>>>(wsb);
  k_attnln<<<atngrid, 256, 0, stream>>>(wsb, ln0_g, ln0_b);
  k_glu   <<<glugrid, 256, 0, stream>>>((const unsigned short*)(wsb + H1B),
                                        (const unsigned short*)(wsb + WBFB) + 32768,
                                        fc_in1_b, fc_out1_b,
                                        (unsigned short*)(wsb + VTB));
  k_initv2<<<128, 256, 0, stream>>>(wsb);
  k_reduce<<<redgrid, 256, 0, stream>>>(wsb, (const unsigned short*)(wsb + VTB),
                                        (float*)(wsb + V2FB));
  k_v2cvt <<<144, 256, 0, stream>>>(wsb);
  k_attnhead<<<atngrid, 256, 0, stream>>>(wsb, ln1_g, ln1_b, W_reg, b_reg, out);
}

// Round 5
// 990.420 us; speedup vs baseline: 1.1607x; 1.1607x over previous
//
#include <hip/hip_runtime.h>

#define NB 4
#define NN 50000

// ---- workspace byte offsets (total ~205.16 MB, < proven 205.9 MB) ----
#define H0B   0L
#define H1B   51200000L
#define VTB   102400000L     // v (GLU out, bf16); before GLU0 doubles as RM + XG
#define RMB   102400000L     // fp32 rm [4*50000]  (consumed by k_kfin, pre-GLU0)
#define XGB   103448576L     // bf16 xg [4*50000][96] (consumed by pass1b, pre-GLU0)
#define QB    153600000L
#define KKB   179200000L
#define WBFB  204800000L     // bf16 GLU weights: layer0 [256][128], layer1 at +65536B
#define V2FB  204931072L     // fp32 v2x [4][64][128]
#define V2TB  205062144L     // bf16 v2x^T+ksum [4][144][64]
#define KSB   205135872L     // fp32 ksum [4][64]
#define GMB   205136896L     // 4 uints
#define W12B  205137920L     // bf16: W1 [32][96], W2 [32][96], proj [64][32]

typedef short short8_t __attribute__((ext_vector_type(8)));
typedef float f32x4 __attribute__((ext_vector_type(4)));

__device__ __forceinline__ unsigned short f2bf(float f){
  unsigned u = __float_as_uint(f);
  return (unsigned short)((u + 0x7FFFu + ((u>>16)&1u)) >> 16);
}
__device__ __forceinline__ float bf2f(unsigned short s){
  return __uint_as_float(((unsigned)s)<<16);
}
__device__ __forceinline__ unsigned pk2(float a, float b){
  return (unsigned)f2bf(a) | ((unsigned)f2bf(b)<<16);
}
__device__ __forceinline__ uint4 pk8(const float* f){
  uint4 o; o.x=pk2(f[0],f[1]); o.y=pk2(f[2],f[3]);
  o.z=pk2(f[4],f[5]); o.w=pk2(f[6],f[7]); return o;
}
__device__ __forceinline__ void up8(uint4 v, float* f){
  f[0]=bf2f((unsigned short)(v.x&0xFFFFu)); f[1]=bf2f((unsigned short)(v.x>>16));
  f[2]=bf2f((unsigned short)(v.y&0xFFFFu)); f[3]=bf2f((unsigned short)(v.y>>16));
  f[4]=bf2f((unsigned short)(v.z&0xFFFFu)); f[5]=bf2f((unsigned short)(v.z>>16));
  f[6]=bf2f((unsigned short)(v.w&0xFFFFu)); f[7]=bf2f((unsigned short)(v.w>>16));
}
__device__ __forceinline__ unsigned encOrd(float f){
  unsigned u = __float_as_uint(f);
  return (u & 0x80000000u) ? ~u : (u | 0x80000000u);
}
__device__ __forceinline__ float decOrd(unsigned u){
  return (u & 0x80000000u) ? __uint_as_float(u & 0x7fffffffu)
                           : __uint_as_float(~u);
}
__device__ __forceinline__ uint2 mku2(unsigned a, unsigned b){ uint2 t; t.x=a; t.y=b; return t; }

// ---- zero ksum + gmax ----
__global__ void k_init0(char* __restrict__ wsb){
  int t = threadIdx.x;
  ((float*)(wsb + KSB))[t] = 0.0f;
  if (t < 4) ((unsigned*)(wsb + GMB))[t] = 0u;
}
// ---- zero v2x fp32 ----
__global__ void k_initv2(char* __restrict__ wsb){
  int i = blockIdx.x*256 + threadIdx.x;
  if (i < 32768) ((float*)(wsb + V2FB))[i] = 0.0f;
}
// ---- GLU weights -> bf16 [n][k] ----
__global__ void k_wcvt(const float* __restrict__ wi0, const float* __restrict__ wo0,
                       const float* __restrict__ wi1, const float* __restrict__ wo1,
                       char* __restrict__ wsb){
  int idx = blockIdx.x*256 + threadIdx.x;
  if (idx >= 65536) return;
  int l = idx >> 15, r = (idx >> 7) & 255, c = idx & 127;
  const float* src = (l==0) ? ((r<128)? wi0 : wo0) : ((r<128)? wi1 : wo1);
  float v = src[(r&127)*128 + c];
  ((unsigned short*)(wsb + WBFB))[l*32768 + r*128 + c] = f2bf(v);
}
// ---- W1,W2 [32][96] and proj [64][32] -> bf16 (direct layout copy) ----
__global__ void k_wcvt2(const float* __restrict__ W1, const float* __restrict__ W2,
                        const float* __restrict__ proj, char* __restrict__ wsb){
  int i = blockIdx.x*256 + threadIdx.x;          // 8192 total
  if (i >= 8192) return;
  unsigned short* dst = (unsigned short*)(wsb + W12B);
  float v;
  if (i < 3072) v = W1[i];
  else if (i < 6144) v = W2[i-3072];
  else v = proj[i-6144];
  dst[i] = f2bf(v);
}

// ---------- pass1a: h0 (W_in matmul + embeddings), xg -> bf16 --------------
__global__ __launch_bounds__(256) void k_pass1a(
  const float* __restrict__ x, const float* __restrict__ node_emb,
  const float* __restrict__ time_emb, const float* __restrict__ week_emb,
  const float* __restrict__ W_in, const float* __restrict__ b_in,
  char* __restrict__ wsb)
{
  const int b = blockIdx.y;
  const int n = blockIdx.x*256 + threadIdx.x;
  if (n >= NN) return;
  const long row = (long)b*NN + n;
  float xr[36];
  {
    const float4* xp = (const float4*)(x + row*36);
    #pragma unroll
    for (int i=0;i<9;i++){ float4 t=xp[i]; xr[4*i]=t.x; xr[4*i+1]=t.y; xr[4*i+2]=t.z; xr[4*i+3]=t.w; }
  }
  int tidx = (int)(xr[34]*288.0f); tidx = tidx<0?0:(tidx>287?287:tidx);
  int widx = (int)(xr[35]);        widx = widx<0?0:(widx>6?6:widx);
  uint4* h0q = (uint4*)(wsb + H0B) + row*16;
  float hh[32];
  #pragma unroll 1
  for (int jj=0;jj<8;jj++){
    #pragma unroll
    for (int jl=0;jl<4;jl++){
      const int j = jj*4+jl;
      const float* w = W_in + j*36;
      float a0=0.f,a1=0.f,a2=0.f,a3=0.f;
      #pragma unroll
      for (int i=0;i<36;i+=4){ a0+=xr[i]*w[i]; a1+=xr[i+1]*w[i+1]; a2+=xr[i+2]*w[i+2]; a3+=xr[i+3]*w[i+3]; }
      hh[j] = b_in[j] + ((a0+a1)+(a2+a3));
    }
  }
  #pragma unroll
  for (int c=0;c<4;c++) h0q[c] = pk8(hh + 8*c);
  float xg[96];
  {
    const float4* p0 = (const float4*)(node_emb + (long)n*32);
    const float4* p1 = (const float4*)(time_emb + (long)tidx*32);
    const float4* p2 = (const float4*)(week_emb + (long)widx*32);
    #pragma unroll
    for (int i=0;i<8;i++){ float4 t=p0[i]; xg[4*i]=t.x; xg[4*i+1]=t.y; xg[4*i+2]=t.z; xg[4*i+3]=t.w; }
    #pragma unroll
    for (int i=0;i<8;i++){ float4 t=p1[i]; xg[32+4*i]=t.x; xg[32+4*i+1]=t.y; xg[32+4*i+2]=t.z; xg[32+4*i+3]=t.w; }
    #pragma unroll
    for (int i=0;i<8;i++){ float4 t=p2[i]; xg[64+4*i]=t.x; xg[64+4*i+1]=t.y; xg[64+4*i+2]=t.z; xg[64+4*i+3]=t.w; }
  }
  #pragma unroll
  for (int c=0;c<12;c++) h0q[4+c] = pk8(xg + 8*c);
  uint4* xgq = (uint4*)(wsb + XGB) + row*12;
  #pragma unroll
  for (int c=0;c<12;c++) xgq[c] = pk8(xg + 8*c);
}

// ---------- pass1b (MFMA): q, k', rm, global key max -----------------------
__global__ __launch_bounds__(256) void k_pass1b(
  const float* __restrict__ b1, const float* __restrict__ b2,
  char* __restrict__ wsb)
{
  __shared__ unsigned short xgt[64][96];     // 12 KB
  __shared__ unsigned short dt[2][64][32];   // 8 KB
  __shared__ unsigned short ot[64][64];      // 8 KB
  __shared__ float wred[4];
  const int b   = blockIdx.y;
  const int tid = threadIdx.x;
  const int lane= tid & 63;
  const int w   = tid >> 6;
  const int c   = lane & 15;
  const int kg  = lane >> 4;
  const long r0blk = (long)blockIdx.x * 64;
  // stage xg tile
  {
    int row = tid >> 2, q3 = tid & 3;
    long gr = r0blk + row;
    uint4 v0={0,0,0,0}, v1=v0, v2=v0;
    if (gr < NN){
      const uint4* src = (const uint4*)(wsb + XGB + ((long)b*NN + gr)*192 + q3*48);
      v0=src[0]; v1=src[1]; v2=src[2];
    }
    uint4* d = (uint4*)&xgt[row][q3*24];
    d[0]=v0; d[1]=v1; d[2]=v2;
  }
  __syncthreads();
  const unsigned short* w1bf = (const unsigned short*)(wsb + W12B);
  const unsigned short* w2bf = w1bf + 3072;
  const unsigned short* pjbf = w1bf + 6144;
  // MFMA 1: d[side] = (xg @ Wside^T + bside) * DSC  (rows w*16..+15)
  f32x4 accd[2][2];
  #pragma unroll
  for (int s=0;s<2;s++)
    #pragma unroll
    for (int f=0;f<2;f++) accd[s][f] = (f32x4){0.f,0.f,0.f,0.f};
  #pragma unroll
  for (int ks=0;ks<3;ks++){
    short8_t a = *(const short8_t*)&xgt[w*16 + c][ks*32 + kg*8];
    #pragma unroll
    for (int f=0;f<2;f++){
      short8_t bw1 = *(const short8_t*)(w1bf + (f*16+c)*96 + ks*32 + kg*8);
      accd[0][f] = __builtin_amdgcn_mfma_f32_16x16x32_bf16(a, bw1, accd[0][f], 0,0,0);
      short8_t bw2 = *(const short8_t*)(w2bf + (f*16+c)*96 + ks*32 + kg*8);
      accd[1][f] = __builtin_amdgcn_mfma_f32_16x16x32_bf16(a, bw2, accd[1][f], 0,0,0);
    }
  }
  const float DSC = 0.42044820762685725f;   // 32^-0.25
  float dv[2][2][4];
  #pragma unroll
  for (int f=0;f<2;f++){
    float bb1 = b1[f*16+c], bb2 = b2[f*16+c];
    #pragma unroll
    for (int jj=0;jj<4;jj++){
      dv[0][f][jj] = (accd[0][f][jj] + bb1) * DSC;
      dv[1][f][jj] = (accd[1][f][jj] + bb2) * DSC;
    }
  }
  // diag = 0.5 * sum_j d^2   (reduce over f in-lane, then 16 c-lanes)
  float dg[2][4];
  #pragma unroll
  for (int s=0;s<2;s++)
    #pragma unroll
    for (int jj=0;jj<4;jj++){
      float t = dv[s][0][jj]*dv[s][0][jj] + dv[s][1][jj]*dv[s][1][jj];
      #pragma unroll
      for (int off=1; off<16; off<<=1) t += __shfl_xor(t, off);
      dg[s][jj] = 0.5f * t;
    }
  // transpose d via LDS (C-layout -> A-layout)
  #pragma unroll
  for (int s=0;s<2;s++)
    #pragma unroll
    for (int f=0;f<2;f++)
      #pragma unroll
      for (int jj=0;jj<4;jj++)
        dt[s][w*16 + kg*4 + jj][f*16 + c] = f2bf(dv[s][f][jj]);
  __syncthreads();
  // MFMA 2: dash[side][m] = d[side] @ proj^T
  f32x4 acc2[2][4];
  #pragma unroll
  for (int s=0;s<2;s++){
    short8_t ad = *(const short8_t*)&dt[s][w*16 + c][kg*8];
    #pragma unroll
    for (int f=0;f<4;f++){
      short8_t bp = *(const short8_t*)(pjbf + (f*16+c)*32 + kg*8);
      acc2[s][f] = __builtin_amdgcn_mfma_f32_16x16x32_bf16(ad, bp, (f32x4){0.f,0.f,0.f,0.f}, 0,0,0);
    }
  }
  // per-row max over m (4 frags in-lane + 16 c-lanes)
  float mx[2][4];
  #pragma unroll
  for (int s=0;s<2;s++)
    #pragma unroll
    for (int jj=0;jj<4;jj++){
      float t = fmaxf(fmaxf(acc2[s][0][jj],acc2[s][1][jj]),
                      fmaxf(acc2[s][2][jj],acc2[s][3][jj]));
      #pragma unroll
      for (int off=1; off<16; off<<=1) t = fmaxf(t, __shfl_xor(t, off));
      mx[s][jj] = t;
    }
  // ---- q tile ----
  #pragma unroll
  for (int f=0;f<4;f++)
    #pragma unroll
    for (int jj=0;jj<4;jj++){
      float qv = 0.125f*(__expf(acc2[0][f][jj] - dg[0][jj] - mx[0][jj]) + 1e-6f);
      ot[w*16 + kg*4 + jj][f*16 + c] = f2bf(qv);
    }
  __syncthreads();
  {
    int row = tid >> 2, q3 = tid & 3;
    long gr = r0blk + row;
    if (gr < NN){
      const uint4* s = (const uint4*)&ot[row][q3*16];
      uint4* dst = (uint4*)((unsigned short*)(wsb + QB) + ((long)b*NN + gr)*64 + q3*16);
      dst[0] = s[0]; dst[1] = s[1];
    }
  }
  __syncthreads();   // WAR: reuse ot for k
  // ---- k' tile + rm + block max ----
  float bmax = -3.0e38f;
  #pragma unroll
  for (int f=0;f<4;f++)
    #pragma unroll
    for (int jj=0;jj<4;jj++){
      float kv = __expf(acc2[1][f][jj] - mx[1][jj]);
      ot[w*16 + kg*4 + jj][f*16 + c] = f2bf(kv);
    }
  #pragma unroll
  for (int jj=0;jj<4;jj++){
    long gr = r0blk + w*16 + kg*4 + jj;
    bool val = (gr < NN);
    if (val && c==0)
      ((float*)(wsb + RMB))[(long)b*NN + gr] = mx[1][jj] - dg[1][jj];
    if (val) bmax = fmaxf(bmax, mx[1][jj]);
  }
  #pragma unroll
  for (int off=32; off>0; off>>=1) bmax = fmaxf(bmax, __shfl_xor(bmax, off));
  if (lane==0) wred[w] = bmax;
  __syncthreads();
  {
    int row = tid >> 2, q3 = tid & 3;
    long gr = r0blk + row;
    if (gr < NN){
      const uint4* s = (const uint4*)&ot[row][q3*16];
      uint4* dst = (uint4*)((unsigned short*)(wsb + KKB) + ((long)b*NN + gr)*64 + q3*16);
      dst[0] = s[0]; dst[1] = s[1];
    }
  }
  if (tid==0){
    float m2 = fmaxf(fmaxf(wred[0],wred[1]), fmaxf(wred[2],wred[3]));
    atomicMax((unsigned*)(wsb + GMB) + b, encOrd(m2));
  }
}

// ---------- finalize k = 0.125*(k'*exp(rm-gmax)+1e-6) ----------------------
__global__ __launch_bounds__(256) void k_kfin(char* __restrict__ wsb){
  const int b = blockIdx.y;
  const int n = blockIdx.x*256 + threadIdx.x;
  if (n >= NN) return;
  const long row = (long)b*NN + n;
  const float gm = decOrd(((const unsigned*)(wsb + GMB))[b]);
  const float scale = __expf(((const float*)(wsb + RMB))[row] - gm);
  uint4* kq = (uint4*)(wsb + KKB) + row*8;
  #pragma unroll
  for (int mm=0;mm<8;mm++){
    float t[8]; up8(kq[mm], t);
    #pragma unroll
    for (int e=0;e<8;e++) t[e] = 0.125f*(t[e]*scale + 1e-6f);
    kq[mm] = pk8(t);
  }
}

// ---------- MFMA GLU with LDS-staged output --------------------------------
__global__ __launch_bounds__(256) void k_glu(
  const unsigned short* __restrict__ h, const unsigned short* __restrict__ wbf,
  const float* __restrict__ bi, const float* __restrict__ bo,
  unsigned short* __restrict__ vout)
{
  __shared__ unsigned short vt[64][132];
  const int tid = threadIdx.x;
  const int lane = tid & 63;
  const int wid  = tid >> 6;
  const int c  = lane & 15;
  const int kg = lane >> 4;
  const long r0blk = (long)blockIdx.x*64;           // 3125*64 = 200000 exact
  const unsigned short* arow = h + (r0blk + wid*16 + c)*128 + kg*8;
  f32x4 acc[16];
  #pragma unroll
  for (int f=0;f<16;f++) acc[f] = (f32x4){0.f,0.f,0.f,0.f};
  #pragma unroll
  for (int ks=0;ks<4;ks++){
    short8_t a = *(const short8_t*)(arow + ks*32);
    #pragma unroll
    for (int f=0;f<16;f++){
      short8_t bb = *(const short8_t*)(wbf + (f*16 + c)*128 + ks*32 + kg*8);
      acc[f] = __builtin_amdgcn_mfma_f32_16x16x32_bf16(a, bb, acc[f], 0, 0, 0);
    }
  }
  float bi_l[8], bo_l[8];
  #pragma unroll
  for (int f=0;f<8;f++){ bi_l[f] = bi[f*16+c]; bo_l[f] = bo[f*16+c]; }
  #pragma unroll
  for (int f=0;f<8;f++){
    #pragma unroll
    for (int j=0;j<4;j++){
      float a  = acc[f][j]   + bi_l[f];
      float cc = acc[f+8][j] + bo_l[f];
      float o  = cc / (1.0f + __expf(-a));
      vt[wid*16 + kg*4 + j][f*16 + c] = f2bf(o);
    }
  }
  __syncthreads();
  {
    int row = tid>>2, q = tid&3;
    const uint2* s = (const uint2*)&vt[row][q*32];
    uint2 a0=s[0],a1=s[1],a2=s[2],a3=s[3],a4=s[4],a5=s[5],a6=s[6],a7=s[7];
    uint4* dst = (uint4*)(vout + (r0blk + row)*128 + q*32);
    uint4 o0; o0.x=a0.x; o0.y=a0.y; o0.z=a1.x; o0.w=a1.y;
    uint4 o1; o1.x=a2.x; o1.y=a2.y; o1.z=a3.x; o1.w=a3.y;
    uint4 o2; o2.x=a4.x; o2.y=a4.y; o2.z=a5.x; o2.w=a5.y;
    uint4 o3; o3.x=a6.x; o3.y=a6.y; o3.z=a7.x; o3.w=a7.y;
    dst[0]=o0; dst[1]=o1; dst[2]=o2; dst[3]=o3;
  }
}

// ---------- ksum ------------------------------------------------------------
__global__ __launch_bounds__(256) void k_ksum(char* __restrict__ wsb){
  const int b = blockIdx.y;
  const int r0 = blockIdx.x*512;
  const int m2 = threadIdx.x & 31;
  const int rq = threadIdx.x >> 5;
  const int rend = min(r0+512, NN);
  const unsigned* kk = (const unsigned*)(wsb + KKB) + (long)b*NN*32;
  float a0=0.f, a1=0.f;
  for (int r=r0+rq; r<rend; r+=8){
    unsigned u = kk[(long)r*32 + m2];
    a0 += bf2f((unsigned short)(u&0xFFFFu));
    a1 += bf2f((unsigned short)(u>>16));
  }
  __shared__ float red0[8][32], red1[8][32];
  red0[rq][m2]=a0; red1[rq][m2]=a1;
  __syncthreads();
  if (threadIdx.x < 32){
    float s0=0.f, s1=0.f;
    #pragma unroll
    for (int q=0;q<8;q++){ s0+=red0[q][threadIdx.x]; s1+=red1[q][threadIdx.x]; }
    float* ks = (float*)(wsb + KSB) + b*64;
    atomicAdd(ks + 2*threadIdx.x,     s0);
    atomicAdd(ks + 2*threadIdx.x + 1, s1);
  }
}

// ---------- v2x[b][m][d] = sum_n k[n][m]*v[n][d] ---------------------------
__global__ __launch_bounds__(256) void k_reduce(const char* __restrict__ wsb,
                                                const unsigned short* __restrict__ vt,
                                                float* __restrict__ v2x)
{
  const int b  = blockIdx.y;
  const int r0 = blockIdx.x*512;
  __shared__ unsigned short klds[64*64];
  __shared__ unsigned short vlds[64*128];
  const int tid = threadIdx.x;
  const int mg = tid >> 4;
  const int dg = tid & 15;
  float acc[4][8];
  #pragma unroll
  for (int f=0;f<4;f++)
    #pragma unroll
    for (int e=0;e<8;e++) acc[f][e]=0.f;
  const uint4* kbase = (const uint4*)(wsb + KKB) + (long)b*NN*8;
  const uint4* vbase = (const uint4*)vt + (long)b*NN*16;
  const int rend = min(r0+512, NN);
  for (int t0=r0; t0<rend; t0+=64){
    __syncthreads();
    #pragma unroll
    for (int e=0;e<2;e++){
      int f = tid + 256*e;
      int rr = f >> 3, cc = f & 7;
      int gr = t0 + rr;
      uint4 val = {0u,0u,0u,0u};
      if (gr < NN) val = kbase[(long)gr*8 + cc];
      ((uint4*)klds)[f] = val;
    }
    #pragma unroll
    for (int e=0;e<4;e++){
      int f = tid + 256*e;
      int rr = f >> 4, cc = f & 15;
      int gr = t0 + rr;
      uint4 val = {0u,0u,0u,0u};
      if (gr < NN) val = vbase[(long)gr*16 + cc];
      ((uint4*)vlds)[f] = val;
    }
    __syncthreads();
    #pragma unroll 2
    for (int r=0;r<64;r++){
      uint2 kv = ((const uint2*)klds)[r*16 + mg];
      uint4 vv = ((const uint4*)vlds)[r*16 + dg];
      float kkv[4] = { bf2f((unsigned short)(kv.x&0xFFFFu)), bf2f((unsigned short)(kv.x>>16)),
                       bf2f((unsigned short)(kv.y&0xFFFFu)), bf2f((unsigned short)(kv.y>>16)) };
      float vvv[8]; up8(vv, vvv);
      #pragma unroll
      for (int f=0;f<4;f++)
        #pragma unroll
        for (int e=0;e<8;e++) acc[f][e] += kkv[f]*vvv[e];
    }
  }
  #pragma unroll
  for (int f=0;f<4;f++)
    #pragma unroll
    for (int e=0;e<8;e++)
      atomicAdd(&v2x[(long)b*8192 + (mg*4+f)*128 + dg*8+e], acc[f][e]);
}

// ---------- v2t[b][n][m]: n<128: v2x[m][n]; n=128: ksum[m]; n>128: 0 -------
__global__ void k_v2cvt(char* __restrict__ wsb){
  int idx = blockIdx.x*256 + threadIdx.x;          // 36864
  if (idx >= 36864) return;
  int b = idx / 9216, rem = idx % 9216;
  int n = rem / 64, m = rem % 64;
  const float* v2f = (const float*)(wsb + V2FB);
  const float* ks  = (const float*)(wsb + KSB);
  float v = (n < 128) ? v2f[b*8192 + m*128 + n] : ((n==128) ? ks[b*64+m] : 0.f);
  ((unsigned short*)(wsb + V2TB))[b*9216 + n*64 + m] = f2bf(v);
}

// ---------- MFMA attn-apply + residual(h0,LDS) + LN -> h1 ------------------
__global__ __launch_bounds__(256) void k_attnln(
  const char* __restrict__ wsb, const float* __restrict__ g0,
  const float* __restrict__ bt0)
{
  __shared__ unsigned short ht[64][132];
  const int b = blockIdx.y;
  const int tid = threadIdx.x;
  const int lane = tid & 63;
  const int wid  = tid >> 6;
  const int c  = lane & 15;
  const int kg = lane >> 4;
  const long r0blk = (long)blockIdx.x*64;
  const unsigned short* h0g = (const unsigned short*)(wsb + H0B);
  unsigned short* h1g = (unsigned short*)(wsb + H1B);
  {
    int row = tid>>2, q = tid&3;
    long gr = r0blk + row;
    uint4 v0={0,0,0,0}, v1=v0, v2=v0, v3=v0;
    if (gr < NN){
      const uint4* src = (const uint4*)(h0g + ((long)b*NN + gr)*128 + q*32);
      v0=src[0]; v1=src[1]; v2=src[2]; v3=src[3];
    }
    uint2* d = (uint2*)&ht[row][q*32];
    d[0]=mku2(v0.x,v0.y); d[1]=mku2(v0.z,v0.w); d[2]=mku2(v1.x,v1.y); d[3]=mku2(v1.z,v1.w);
    d[4]=mku2(v2.x,v2.y); d[5]=mku2(v2.z,v2.w); d[6]=mku2(v3.x,v3.y); d[7]=mku2(v3.z,v3.w);
  }
  __syncthreads();
  const long r0w = r0blk + wid*16;
  const unsigned short* v2t = (const unsigned short*)(wsb + V2TB) + b*9216;
  short8_t aq[2];
  if (r0w + c < NN){
    const unsigned short* qrow = (const unsigned short*)(wsb + QB) + ((long)b*NN + r0w + c)*64 + kg*8;
    aq[0] = *(const short8_t*)(qrow);
    aq[1] = *(const short8_t*)(qrow + 32);
  } else {
    aq[0] = (short8_t){0,0,0,0,0,0,0,0};
    aq[1] = (short8_t){0,0,0,0,0,0,0,0};
  }
  f32x4 acc[9];
  #pragma unroll
  for (int f=0;f<9;f++) acc[f] = (f32x4){0.f,0.f,0.f,0.f};
  #pragma unroll
  for (int ks=0;ks<2;ks++){
    #pragma unroll
    for (int f=0;f<9;f++){
      short8_t bb = *(const short8_t*)(v2t + (f*16 + c)*64 + ks*32 + kg*8);
      acc[f] = __builtin_amdgcn_mfma_f32_16x16x32_bf16(aq[ks], bb, acc[f], 0, 0, 0);
    }
  }
  float inv[4];
  #pragma unroll
  for (int j=0;j<4;j++){
    float o2 = __shfl(acc[8][j], (lane & 48));
    inv[j] = 1.0f / o2;
  }
  float t[8][4];
  #pragma unroll
  for (int f=0;f<8;f++)
    #pragma unroll
    for (int j=0;j<4;j++)
      t[f][j] = acc[f][j]*inv[j] + bf2f(ht[wid*16 + kg*4 + j][f*16 + c]);
  float mu[4], rs[4];
  #pragma unroll
  for (int j=0;j<4;j++){
    float s = 0.f;
    #pragma unroll
    for (int f=0;f<8;f++) s += t[f][j];
    #pragma unroll
    for (int off=1; off<16; off<<=1) s += __shfl_xor(s, off);
    mu[j] = s * (1.0f/128.0f);
  }
  #pragma unroll
  for (int j=0;j<4;j++){
    float s = 0.f;
    #pragma unroll
    for (int f=0;f<8;f++){ float e = t[f][j]-mu[j]; s += e*e; }
    #pragma unroll
    for (int off=1; off<16; off<<=1) s += __shfl_xor(s, off);
    rs[j] = rsqrtf(s * (1.0f/128.0f) + 1e-5f);
  }
  float g_l[8], bt_l[8];
  #pragma unroll
  for (int f=0;f<8;f++){ g_l[f] = g0[f*16+c]; bt_l[f] = bt0[f*16+c]; }
  #pragma unroll
  for (int f=0;f<8;f++)
    #pragma unroll
    for (int j=0;j<4;j++){
      float o = (t[f][j]-mu[j])*rs[j]*g_l[f] + bt_l[f];
      ht[wid*16 + kg*4 + j][f*16 + c] = f2bf(o);
    }
  __syncthreads();
  {
    int row = tid>>2, q = tid&3;
    long gr = r0blk + row;
    if (gr < NN){
      const uint2* s = (const uint2*)&ht[row][q*32];
      uint2 a0=s[0],a1=s[1],a2=s[2],a3=s[3],a4=s[4],a5=s[5],a6=s[6],a7=s[7];
      uint4* dst = (uint4*)(h1g + ((long)b*NN + gr)*128 + q*32);
      uint4 o0; o0.x=a0.x; o0.y=a0.y; o0.z=a1.x; o0.w=a1.y;
      uint4 o1; o1.x=a2.x; o1.y=a2.y; o1.z=a3.x; o1.w=a3.y;
      uint4 o2; o2.x=a4.x; o2.y=a4.y; o2.z=a5.x; o2.w=a5.y;
      uint4 o3; o3.x=a6.x; o3.y=a6.y; o3.z=a7.x; o3.w=a7.y;
      dst[0]=o0; dst[1]=o1; dst[2]=o2; dst[3]=o3;
    }
  }
}

// ---------- MFMA attn-apply + residual(h1) + LN1 + regression head ---------
__global__ __launch_bounds__(256) void k_attnhead(
  const char* __restrict__ wsb, const float* __restrict__ g1,
  const float* __restrict__ bt1, const float* __restrict__ W_reg,
  const float* __restrict__ b_reg, float* __restrict__ out)
{
  __shared__ unsigned short ht[64][132];
  const int b = blockIdx.y;
  const int tid = threadIdx.x;
  const int lane = tid & 63;
  const int wid  = tid >> 6;
  const int c  = lane & 15;
  const int kg = lane >> 4;
  const long r0blk = (long)blockIdx.x*64;
  const unsigned short* h0g = (const unsigned short*)(wsb + H0B);
  const unsigned short* h1g = (const unsigned short*)(wsb + H1B);
  {
    int row = tid>>2, q = tid&3;
    long gr = r0blk + row;
    uint4 v0={0,0,0,0}, v1=v0, v2=v0, v3=v0;
    if (gr < NN){
      const uint4* src = (const uint4*)(h1g + ((long)b*NN + gr)*128 + q*32);
      v0=src[0]; v1=src[1]; v2=src[2]; v3=src[3];
    }
    uint2* d = (uint2*)&ht[row][q*32];
    d[0]=mku2(v0.x,v0.y); d[1]=mku2(v0.z,v0.w); d[2]=mku2(v1.x,v1.y); d[3]=mku2(v1.z,v1.w);
    d[4]=mku2(v2.x,v2.y); d[5]=mku2(v2.z,v2.w); d[6]=mku2(v3.x,v3.y); d[7]=mku2(v3.z,v3.w);
  }
  __syncthreads();
  const long r0w = r0blk + wid*16;
  const unsigned short* v2t = (const unsigned short*)(wsb + V2TB) + b*9216;
  short8_t aq[2];
  if (r0w + c < NN){
    const unsigned short* qrow = (const unsigned short*)(wsb + QB) + ((long)b*NN + r0w + c)*64 + kg*8;
    aq[0] = *(const short8_t*)(qrow);
    aq[1] = *(const short8_t*)(qrow + 32);
  } else {
    aq[0] = (short8_t){0,0,0,0,0,0,0,0};
    aq[1] = (short8_t){0,0,0,0,0,0,0,0};
  }
  f32x4 acc[9];
  #pragma unroll
  for (int f=0;f<9;f++) acc[f] = (f32x4){0.f,0.f,0.f,0.f};
  #pragma unroll
  for (int ks=0;ks<2;ks++){
    #pragma unroll
    for (int f=0;f<9;f++){
      short8_t bb = *(const short8_t*)(v2t + (f*16 + c)*64 + ks*32 + kg*8);
      acc[f] = __builtin_amdgcn_mfma_f32_16x16x32_bf16(aq[ks], bb, acc[f], 0, 0, 0);
    }
  }
  float inv[4];
  #pragma unroll
  for (int j=0;j<4;j++){
    float o2 = __shfl(acc[8][j], (lane & 48));
    inv[j] = 1.0f / o2;
  }
  float t[8][4];
  #pragma unroll
  for (int f=0;f<8;f++)
    #pragma unroll
    for (int j=0;j<4;j++)
      t[f][j] = acc[f][j]*inv[j] + bf2f(ht[wid*16 + kg*4 + j][f*16 + c]);
  float mu[4], rs[4];
  #pragma unroll
  for (int j=0;j<4;j++){
    float s = 0.f;
    #pragma unroll
    for (int f=0;f<8;f++) s += t[f][j];
    #pragma unroll
    for (int off=1; off<16; off<<=1) s += __shfl_xor(s, off);
    mu[j] = s * (1.0f/128.0f);
  }
  #pragma unroll
  for (int j=0;j<4;j++){
    float s = 0.f;
    #pragma unroll
    for (int f=0;f<8;f++){ float e = t[f][j]-mu[j]; s += e*e; }
    #pragma unroll
    for (int off=1; off<16; off<<=1) s += __shfl_xor(s, off);
    rs[j] = rsqrtf(s * (1.0f/128.0f) + 1e-5f);
  }
  float g_l[8], bt_l[8];
  #pragma unroll
  for (int f=0;f<8;f++){ g_l[f] = g1[f*16+c]; bt_l[f] = bt1[f*16+c]; }
  #pragma unroll
  for (int f=0;f<8;f++)
    #pragma unroll
    for (int j=0;j<4;j++)
      t[f][j] = fmaxf((t[f][j]-mu[j])*rs[j]*g_l[f] + bt_l[f], 0.f);
  __syncthreads();
  {
    int row = tid>>2, q = tid&3;
    long gr = r0blk + row;
    uint4 v0={0,0,0,0}, v1=v0, v2=v0, v3=v0;
    if (gr < NN){
      const uint4* src = (const uint4*)(h0g + ((long)b*NN + gr)*128 + q*32);
      v0=src[0]; v1=src[1]; v2=src[2]; v3=src[3];
    }
    uint2* d = (uint2*)&ht[row][q*32];
    d[0]=mku2(v0.x,v0.y); d[1]=mku2(v0.z,v0.w); d[2]=mku2(v1.x,v1.y); d[3]=mku2(v1.z,v1.w);
    d[4]=mku2(v2.x,v2.y); d[5]=mku2(v2.z,v2.w); d[6]=mku2(v3.x,v3.y); d[7]=mku2(v3.z,v3.w);
  }
  __syncthreads();
  float y[12][4];
  #pragma unroll
  for (int tt=0;tt<12;tt++)
    #pragma unroll
    for (int j=0;j<4;j++) y[tt][j] = 0.f;
  #pragma unroll
  for (int f=0;f<8;f++){
    float u0j[4];
    #pragma unroll
    for (int j=0;j<4;j++)
      u0j[j] = fmaxf(bf2f(ht[wid*16 + kg*4 + j][f*16 + c]), 0.f);
    #pragma unroll
    for (int tt=0;tt<12;tt++){
      float wl = W_reg[tt*256 + f*16 + c];
      float wh = W_reg[tt*256 + 128 + f*16 + c];
      #pragma unroll
      for (int j=0;j<4;j++) y[tt][j] += u0j[j]*wl + t[f][j]*wh;
    }
  }
  #pragma unroll
  for (int tt=0;tt<12;tt++)
    #pragma unroll
    for (int j=0;j<4;j++){
      float s = y[tt][j];
      #pragma unroll
      for (int off=1; off<16; off<<=1) s += __shfl_xor(s, off);
      long gr = r0w + kg*4 + j;
      if (c == tt && gr < NN)
        out[((long)b*12 + tt)*NN + gr] = s + b_reg[tt];
    }
}

extern "C" void kernel_launch(void* const* d_in, const int* in_sizes, int n_in,
                              void* d_out, int out_size, void* d_ws, size_t ws_size,
                              hipStream_t stream)
{
  const float* x        = (const float*)d_in[0];
  const float* node_emb = (const float*)d_in[1];
  const float* time_emb = (const float*)d_in[2];
  const float* week_emb = (const float*)d_in[3];
  const float* W_in     = (const float*)d_in[4];
  const float* b_in     = (const float*)d_in[5];
  const float* W1       = (const float*)d_in[6];
  const float* b1       = (const float*)d_in[7];
  const float* W2       = (const float*)d_in[8];
  const float* b2       = (const float*)d_in[9];
  const float* W_reg    = (const float*)d_in[10];
  const float* b_reg    = (const float*)d_in[11];
  const float* proj     = (const float*)d_in[12];
  const float* fc_in0_w = (const float*)d_in[13];
  const float* fc_in0_b = (const float*)d_in[14];
  const float* fc_out0_w= (const float*)d_in[15];
  const float* fc_out0_b= (const float*)d_in[16];
  const float* ln0_g    = (const float*)d_in[17];
  const float* ln0_b    = (const float*)d_in[18];
  const float* fc_in1_w = (const float*)d_in[19];
  const float* fc_in1_b = (const float*)d_in[20];
  const float* fc_out1_w= (const float*)d_in[21];
  const float* fc_out1_b= (const float*)d_in[22];
  const float* ln1_g    = (const float*)d_in[23];
  const float* ln1_b    = (const float*)d_in[24];
  char* wsb  = (char*)d_ws;
  float* out = (float*)d_out;

  dim3 rowgrid((NN+255)/256, NB);     // (196, 4)
  dim3 redgrid((NN+511)/512, NB);     // (98, 4)
  dim3 glugrid(3125);                 // 3125*64 = 200000 rows
  dim3 atngrid(782, NB);              // 782*64 = 50048 >= NN

  k_init0 <<<1, 256, 0, stream>>>(wsb);
  k_wcvt  <<<256, 256, 0, stream>>>(fc_in0_w, fc_out0_w, fc_in1_w, fc_out1_w, wsb);
  k_wcvt2 <<<32, 256, 0, stream>>>(W1, W2, proj, wsb);
  k_pass1a<<<rowgrid, 256, 0, stream>>>(x, node_emb, time_emb, week_emb,
                                        W_in, b_in, wsb);
  k_pass1b<<<atngrid, 256, 0, stream>>>(b1, b2, wsb);
  k_kfin  <<<rowgrid, 256, 0, stream>>>(wsb);
  k_glu   <<<glugrid, 256, 0, stream>>>((const unsigned short*)(wsb + H0B),
                                        (const unsigned short*)(wsb + WBFB),
                                        fc_in0_b, fc_out0_b,
                                        (unsigned short*)(wsb + VTB));
  k_ksum  <<<redgrid, 256, 0, stream>>>(wsb);
  k_initv2<<<128, 256, 0, stream>>>(wsb);
  k_reduce<<<redgrid, 256, 0, stream>>>(wsb, (const unsigned short*)(wsb + VTB),
                                        (float*)(wsb + V2FB));
  k_v2cvt <<<144, 256, 0, stream>>>(wsb);
  k_attnln<<<atngrid, 256, 0, stream>>>(wsb, ln0_g, ln0_b);
  k_glu   <<<glugrid, 256, 0, stream>>>((const unsigned short*)(wsb + H1B),
                                        (const unsigned short*)(wsb + WBFB) + 32768,
                                        fc_in1_b, fc_out1_b,
                                        (unsigned short*)(wsb + VTB));
  k_initv2<<<128, 256, 0, stream>>>(wsb);
  k_reduce<<<redgrid, 256, 0, stream>>>(wsb, (const unsigned short*)(wsb + VTB),
                                        (float*)(wsb + V2FB));
  k_v2cvt <<<144, 256, 0, stream>>>(wsb);
  k_attnhead<<<atngrid, 256, 0, stream>>>(wsb, ln1_g, ln1_b, W_reg, b_reg, out);
}

// Round 6
// 863.422 us; speedup vs baseline: 1.3314x; 1.1471x over previous
//
#include <hip/hip_runtime.h>

#define NB 4
#define NN 50000

// ---- workspace byte offsets (total ~205.16 MB, < proven 205.9 MB) ----
#define H0B   0L
#define H1B   51200000L
#define VTB   102400000L     // v (GLU out, bf16); before GLU0 doubles as RM + XG
#define RMB   102400000L     // fp32 rm [4*50000]  (consumed by k_kfin, pre-GLU0)
#define XGB   103448576L     // bf16 xg [4*50000][96] (consumed by pass1b, pre-GLU0)
#define QB    153600000L
#define KKB   179200000L
#define WBFB  204800000L     // bf16 GLU weights: layer0 [256][128], layer1 at +65536B
#define V2FB  204931072L     // fp32 v2x [4][64][128]
#define V2TB  205062144L     // bf16 v2x^T+ksum [4][144][64]
#define KSB   205135872L     // fp32 ksum [4][64]
#define GMB   205136896L     // 4 uints
#define W12B  205137920L     // bf16: W1 [32][96], W2 [32][96], proj [64][32], W_regT [16][256]

typedef short short8_t __attribute__((ext_vector_type(8)));
typedef float f32x4 __attribute__((ext_vector_type(4)));

__device__ __forceinline__ unsigned short f2bf(float f){
  unsigned u = __float_as_uint(f);
  return (unsigned short)((u + 0x7FFFu + ((u>>16)&1u)) >> 16);
}
__device__ __forceinline__ float bf2f(unsigned short s){
  return __uint_as_float(((unsigned)s)<<16);
}
__device__ __forceinline__ unsigned pk2(float a, float b){
  return (unsigned)f2bf(a) | ((unsigned)f2bf(b)<<16);
}
__device__ __forceinline__ uint4 pk8(const float* f){
  uint4 o; o.x=pk2(f[0],f[1]); o.y=pk2(f[2],f[3]);
  o.z=pk2(f[4],f[5]); o.w=pk2(f[6],f[7]); return o;
}
__device__ __forceinline__ void up8(uint4 v, float* f){
  f[0]=bf2f((unsigned short)(v.x&0xFFFFu)); f[1]=bf2f((unsigned short)(v.x>>16));
  f[2]=bf2f((unsigned short)(v.y&0xFFFFu)); f[3]=bf2f((unsigned short)(v.y>>16));
  f[4]=bf2f((unsigned short)(v.z&0xFFFFu)); f[5]=bf2f((unsigned short)(v.z>>16));
  f[6]=bf2f((unsigned short)(v.w&0xFFFFu)); f[7]=bf2f((unsigned short)(v.w>>16));
}
__device__ __forceinline__ short8_t relu8(short8_t s){
  short8_t r;
  #pragma unroll
  for (int i=0;i<8;i++){ short v = s[i]; r[i] = (v & (short)0x8000) ? (short)0 : v; }
  return r;
}
__device__ __forceinline__ unsigned encOrd(float f){
  unsigned u = __float_as_uint(f);
  return (u & 0x80000000u) ? ~u : (u | 0x80000000u);
}
__device__ __forceinline__ float decOrd(unsigned u){
  return (u & 0x80000000u) ? __uint_as_float(u & 0x7fffffffu)
                           : __uint_as_float(~u);
}

// ---- zero ksum + gmax ----
__global__ void k_init0(char* __restrict__ wsb){
  int t = threadIdx.x;
  ((float*)(wsb + KSB))[t] = 0.0f;
  if (t < 4) ((unsigned*)(wsb + GMB))[t] = 0u;
}
// ---- zero v2x fp32 ----
__global__ void k_initv2(char* __restrict__ wsb){
  int i = blockIdx.x*256 + threadIdx.x;
  if (i < 32768) ((float*)(wsb + V2FB))[i] = 0.0f;
}
// ---- GLU weights -> bf16 [n][k] ----
__global__ void k_wcvt(const float* __restrict__ wi0, const float* __restrict__ wo0,
                       const float* __restrict__ wi1, const float* __restrict__ wo1,
                       char* __restrict__ wsb){
  int idx = blockIdx.x*256 + threadIdx.x;
  if (idx >= 65536) return;
  int l = idx >> 15, r = (idx >> 7) & 255, c = idx & 127;
  const float* src = (l==0) ? ((r<128)? wi0 : wo0) : ((r<128)? wi1 : wo1);
  float v = src[(r&127)*128 + c];
  ((unsigned short*)(wsb + WBFB))[l*32768 + r*128 + c] = f2bf(v);
}
// ---- W1,W2 [32][96], proj [64][32], W_regT [16][256] -> bf16 --------------
__global__ void k_wcvt2(const float* __restrict__ W1, const float* __restrict__ W2,
                        const float* __restrict__ proj, const float* __restrict__ W_reg,
                        char* __restrict__ wsb){
  int i = blockIdx.x*256 + threadIdx.x;          // 12288 total
  if (i >= 12288) return;
  unsigned short* dst = (unsigned short*)(wsb + W12B);
  float v;
  if (i < 3072) v = W1[i];
  else if (i < 6144) v = W2[i-3072];
  else if (i < 8192) v = proj[i-6144];
  else {
    int r = (i-8192) >> 8, c = (i-8192) & 255;
    v = (r < 12) ? W_reg[r*256 + c] : 0.f;
  }
  dst[i] = f2bf(v);
}

// ---------- pass1a: h0 (W_in matmul + embeddings), xg -> bf16 --------------
__global__ __launch_bounds__(256) void k_pass1a(
  const float* __restrict__ x, const float* __restrict__ node_emb,
  const float* __restrict__ time_emb, const float* __restrict__ week_emb,
  const float* __restrict__ W_in, const float* __restrict__ b_in,
  char* __restrict__ wsb)
{
  const int b = blockIdx.y;
  const int n = blockIdx.x*256 + threadIdx.x;
  if (n >= NN) return;
  const long row = (long)b*NN + n;
  float xr[36];
  {
    const float4* xp = (const float4*)(x + row*36);
    #pragma unroll
    for (int i=0;i<9;i++){ float4 t=xp[i]; xr[4*i]=t.x; xr[4*i+1]=t.y; xr[4*i+2]=t.z; xr[4*i+3]=t.w; }
  }
  int tidx = (int)(xr[34]*288.0f); tidx = tidx<0?0:(tidx>287?287:tidx);
  int widx = (int)(xr[35]);        widx = widx<0?0:(widx>6?6:widx);
  uint4* h0q = (uint4*)(wsb + H0B) + row*16;
  float hh[32];
  #pragma unroll 1
  for (int jj=0;jj<8;jj++){
    #pragma unroll
    for (int jl=0;jl<4;jl++){
      const int j = jj*4+jl;
      const float* w = W_in + j*36;
      float a0=0.f,a1=0.f,a2=0.f,a3=0.f;
      #pragma unroll
      for (int i=0;i<36;i+=4){ a0+=xr[i]*w[i]; a1+=xr[i+1]*w[i+1]; a2+=xr[i+2]*w[i+2]; a3+=xr[i+3]*w[i+3]; }
      hh[j] = b_in[j] + ((a0+a1)+(a2+a3));
    }
  }
  #pragma unroll
  for (int c=0;c<4;c++) h0q[c] = pk8(hh + 8*c);
  float xg[96];
  {
    const float4* p0 = (const float4*)(node_emb + (long)n*32);
    const float4* p1 = (const float4*)(time_emb + (long)tidx*32);
    const float4* p2 = (const float4*)(week_emb + (long)widx*32);
    #pragma unroll
    for (int i=0;i<8;i++){ float4 t=p0[i]; xg[4*i]=t.x; xg[4*i+1]=t.y; xg[4*i+2]=t.z; xg[4*i+3]=t.w; }
    #pragma unroll
    for (int i=0;i<8;i++){ float4 t=p1[i]; xg[32+4*i]=t.x; xg[32+4*i+1]=t.y; xg[32+4*i+2]=t.z; xg[32+4*i+3]=t.w; }
    #pragma unroll
    for (int i=0;i<8;i++){ float4 t=p2[i]; xg[64+4*i]=t.x; xg[64+4*i+1]=t.y; xg[64+4*i+2]=t.z; xg[64+4*i+3]=t.w; }
  }
  #pragma unroll
  for (int c=0;c<12;c++) h0q[4+c] = pk8(xg + 8*c);
  uint4* xgq = (uint4*)(wsb + XGB) + row*12;
  #pragma unroll
  for (int c=0;c<12;c++) xgq[c] = pk8(xg + 8*c);
}

// ---------- pass1b (MFMA): q, k', rm, global key max -----------------------
__global__ __launch_bounds__(256) void k_pass1b(
  const float* __restrict__ b1, const float* __restrict__ b2,
  char* __restrict__ wsb)
{
  __shared__ unsigned short xgt[64][96];
  __shared__ unsigned short dt[2][64][32];
  __shared__ unsigned short ot[64][64];
  __shared__ float wred[4];
  const int b   = blockIdx.y;
  const int tid = threadIdx.x;
  const int lane= tid & 63;
  const int w   = tid >> 6;
  const int c   = lane & 15;
  const int kg  = lane >> 4;
  const long r0blk = (long)blockIdx.x * 64;
  {
    int row = tid >> 2, q3 = tid & 3;
    long gr = r0blk + row;
    uint4 v0={0,0,0,0}, v1=v0, v2=v0;
    if (gr < NN){
      const uint4* src = (const uint4*)(wsb + XGB + ((long)b*NN + gr)*192 + q3*48);
      v0=src[0]; v1=src[1]; v2=src[2];
    }
    uint4* d = (uint4*)&xgt[row][q3*24];
    d[0]=v0; d[1]=v1; d[2]=v2;
  }
  __syncthreads();
  const unsigned short* w1bf = (const unsigned short*)(wsb + W12B);
  const unsigned short* w2bf = w1bf + 3072;
  const unsigned short* pjbf = w1bf + 6144;
  f32x4 accd[2][2];
  #pragma unroll
  for (int s=0;s<2;s++)
    #pragma unroll
    for (int f=0;f<2;f++) accd[s][f] = (f32x4){0.f,0.f,0.f,0.f};
  #pragma unroll
  for (int ks=0;ks<3;ks++){
    short8_t a = *(const short8_t*)&xgt[w*16 + c][ks*32 + kg*8];
    #pragma unroll
    for (int f=0;f<2;f++){
      short8_t bw1 = *(const short8_t*)(w1bf + (f*16+c)*96 + ks*32 + kg*8);
      accd[0][f] = __builtin_amdgcn_mfma_f32_16x16x32_bf16(a, bw1, accd[0][f], 0,0,0);
      short8_t bw2 = *(const short8_t*)(w2bf + (f*16+c)*96 + ks*32 + kg*8);
      accd[1][f] = __builtin_amdgcn_mfma_f32_16x16x32_bf16(a, bw2, accd[1][f], 0,0,0);
    }
  }
  const float DSC = 0.42044820762685725f;   // 32^-0.25
  float dv[2][2][4];
  #pragma unroll
  for (int f=0;f<2;f++){
    float bb1 = b1[f*16+c], bb2 = b2[f*16+c];
    #pragma unroll
    for (int jj=0;jj<4;jj++){
      dv[0][f][jj] = (accd[0][f][jj] + bb1) * DSC;
      dv[1][f][jj] = (accd[1][f][jj] + bb2) * DSC;
    }
  }
  float dg[2][4];
  #pragma unroll
  for (int s=0;s<2;s++)
    #pragma unroll
    for (int jj=0;jj<4;jj++){
      float t = dv[s][0][jj]*dv[s][0][jj] + dv[s][1][jj]*dv[s][1][jj];
      #pragma unroll
      for (int off=1; off<16; off<<=1) t += __shfl_xor(t, off);
      dg[s][jj] = 0.5f * t;
    }
  #pragma unroll
  for (int s=0;s<2;s++)
    #pragma unroll
    for (int f=0;f<2;f++)
      #pragma unroll
      for (int jj=0;jj<4;jj++)
        dt[s][w*16 + kg*4 + jj][f*16 + c] = f2bf(dv[s][f][jj]);
  __syncthreads();
  f32x4 acc2[2][4];
  #pragma unroll
  for (int s=0;s<2;s++){
    short8_t ad = *(const short8_t*)&dt[s][w*16 + c][kg*8];
    #pragma unroll
    for (int f=0;f<4;f++){
      short8_t bp = *(const short8_t*)(pjbf + (f*16+c)*32 + kg*8);
      acc2[s][f] = __builtin_amdgcn_mfma_f32_16x16x32_bf16(ad, bp, (f32x4){0.f,0.f,0.f,0.f}, 0,0,0);
    }
  }
  float mx[2][4];
  #pragma unroll
  for (int s=0;s<2;s++)
    #pragma unroll
    for (int jj=0;jj<4;jj++){
      float t = fmaxf(fmaxf(acc2[s][0][jj],acc2[s][1][jj]),
                      fmaxf(acc2[s][2][jj],acc2[s][3][jj]));
      #pragma unroll
      for (int off=1; off<16; off<<=1) t = fmaxf(t, __shfl_xor(t, off));
      mx[s][jj] = t;
    }
  #pragma unroll
  for (int f=0;f<4;f++)
    #pragma unroll
    for (int jj=0;jj<4;jj++){
      float qv = 0.125f*(__expf(acc2[0][f][jj] - dg[0][jj] - mx[0][jj]) + 1e-6f);
      ot[w*16 + kg*4 + jj][f*16 + c] = f2bf(qv);
    }
  __syncthreads();
  {
    int row = tid >> 2, q3 = tid & 3;
    long gr = r0blk + row;
    if (gr < NN){
      const uint4* s = (const uint4*)&ot[row][q3*16];
      uint4* dst = (uint4*)((unsigned short*)(wsb + QB) + ((long)b*NN + gr)*64 + q3*16);
      dst[0] = s[0]; dst[1] = s[1];
    }
  }
  __syncthreads();
  float bmax = -3.0e38f;
  #pragma unroll
  for (int f=0;f<4;f++)
    #pragma unroll
    for (int jj=0;jj<4;jj++){
      float kv = __expf(acc2[1][f][jj] - mx[1][jj]);
      ot[w*16 + kg*4 + jj][f*16 + c] = f2bf(kv);
    }
  #pragma unroll
  for (int jj=0;jj<4;jj++){
    long gr = r0blk + w*16 + kg*4 + jj;
    bool val = (gr < NN);
    if (val && c==0)
      ((float*)(wsb + RMB))[(long)b*NN + gr] = mx[1][jj] - dg[1][jj];
    if (val) bmax = fmaxf(bmax, mx[1][jj]);
  }
  #pragma unroll
  for (int off=32; off>0; off>>=1) bmax = fmaxf(bmax, __shfl_xor(bmax, off));
  if (lane==0) wred[w] = bmax;
  __syncthreads();
  {
    int row = tid >> 2, q3 = tid & 3;
    long gr = r0blk + row;
    if (gr < NN){
      const uint4* s = (const uint4*)&ot[row][q3*16];
      uint4* dst = (uint4*)((unsigned short*)(wsb + KKB) + ((long)b*NN + gr)*64 + q3*16);
      dst[0] = s[0]; dst[1] = s[1];
    }
  }
  if (tid==0){
    float m2 = fmaxf(fmaxf(wred[0],wred[1]), fmaxf(wred[2],wred[3]));
    atomicMax((unsigned*)(wsb + GMB) + b, encOrd(m2));
  }
}

// ---------- finalize k = 0.125*(k'*exp(rm-gmax)+1e-6) ----------------------
__global__ __launch_bounds__(256) void k_kfin(char* __restrict__ wsb){
  const int b = blockIdx.y;
  const int n = blockIdx.x*256 + threadIdx.x;
  if (n >= NN) return;
  const long row = (long)b*NN + n;
  const float gm = decOrd(((const unsigned*)(wsb + GMB))[b]);
  const float scale = __expf(((const float*)(wsb + RMB))[row] - gm);
  uint4* kq = (uint4*)(wsb + KKB) + row*8;
  #pragma unroll
  for (int mm=0;mm<8;mm++){
    float t[8]; up8(kq[mm], t);
    #pragma unroll
    for (int e=0;e<8;e++) t[e] = 0.125f*(t[e]*scale + 1e-6f);
    kq[mm] = pk8(t);
  }
}

// ---------- MFMA GLU (layer 0) with LDS-staged output ----------------------
__global__ __launch_bounds__(256) void k_glu(
  const unsigned short* __restrict__ h, const unsigned short* __restrict__ wbf,
  const float* __restrict__ bi, const float* __restrict__ bo,
  unsigned short* __restrict__ vout)
{
  __shared__ unsigned short vt[64][132];
  const int tid = threadIdx.x;
  const int lane = tid & 63;
  const int wid  = tid >> 6;
  const int c  = lane & 15;
  const int kg = lane >> 4;
  const long r0blk = (long)blockIdx.x*64;
  const unsigned short* arow = h + (r0blk + wid*16 + c)*128 + kg*8;
  f32x4 acc[16];
  #pragma unroll
  for (int f=0;f<16;f++) acc[f] = (f32x4){0.f,0.f,0.f,0.f};
  #pragma unroll
  for (int ks=0;ks<4;ks++){
    short8_t a = *(const short8_t*)(arow + ks*32);
    #pragma unroll
    for (int f=0;f<16;f++){
      short8_t bb = *(const short8_t*)(wbf + (f*16 + c)*128 + ks*32 + kg*8);
      acc[f] = __builtin_amdgcn_mfma_f32_16x16x32_bf16(a, bb, acc[f], 0, 0, 0);
    }
  }
  float bi_l[8], bo_l[8];
  #pragma unroll
  for (int f=0;f<8;f++){ bi_l[f] = bi[f*16+c]; bo_l[f] = bo[f*16+c]; }
  #pragma unroll
  for (int f=0;f<8;f++){
    #pragma unroll
    for (int j=0;j<4;j++){
      float a  = acc[f][j]   + bi_l[f];
      float cc = acc[f+8][j] + bo_l[f];
      float o  = cc / (1.0f + __expf(-a));
      vt[wid*16 + kg*4 + j][f*16 + c] = f2bf(o);
    }
  }
  __syncthreads();
  {
    int row = tid>>2, q = tid&3;
    const uint4* s = (const uint4*)&vt[row][q*32];
    uint4 o0=s[0],o1=s[1],o2=s[2],o3=s[3];
    uint4* dst = (uint4*)(vout + (r0blk + row)*128 + q*32);
    dst[0]=o0; dst[1]=o1; dst[2]=o2; dst[3]=o3;
  }
}

// ---------- v2x[b][m][d] = sum_n k[n][m]*v[n][d]  (+ optional ksum) --------
__global__ __launch_bounds__(256) void k_reduce(const char* __restrict__ wsb,
                                                const unsigned short* __restrict__ vt,
                                                float* __restrict__ v2x,
                                                float* __restrict__ ksout)
{
  const int b  = blockIdx.y;
  const int r0 = blockIdx.x*512;
  __shared__ unsigned short klds[64*64];
  __shared__ unsigned short vlds[64*128];
  const int tid = threadIdx.x;
  const int mg = tid >> 4;
  const int dg = tid & 15;
  float acc[4][8];
  #pragma unroll
  for (int f=0;f<4;f++)
    #pragma unroll
    for (int e=0;e<8;e++) acc[f][e]=0.f;
  float ksacc = 0.f;
  const uint4* kbase = (const uint4*)(wsb + KKB) + (long)b*NN*8;
  const uint4* vbase = (const uint4*)vt + (long)b*NN*16;
  const int rend = min(r0+512, NN);
  for (int t0=r0; t0<rend; t0+=64){
    __syncthreads();
    #pragma unroll
    for (int e=0;e<2;e++){
      int f = tid + 256*e;
      int rr = f >> 3, cc = f & 7;
      int gr = t0 + rr;
      uint4 val = {0u,0u,0u,0u};
      if (gr < NN) val = kbase[(long)gr*8 + cc];
      ((uint4*)klds)[f] = val;
    }
    #pragma unroll
    for (int e=0;e<4;e++){
      int f = tid + 256*e;
      int rr = f >> 4, cc = f & 15;
      int gr = t0 + rr;
      uint4 val = {0u,0u,0u,0u};
      if (gr < NN) val = vbase[(long)gr*16 + cc];
      ((uint4*)vlds)[f] = val;
    }
    __syncthreads();
    if (ksout){
      for (int r = (tid>>6); r<64; r+=4) ksacc += bf2f(klds[r*64 + (tid&63)]);
    }
    #pragma unroll 2
    for (int r=0;r<64;r++){
      uint2 kv = ((const uint2*)klds)[r*16 + mg];
      uint4 vv = ((const uint4*)vlds)[r*16 + dg];
      float kkv[4] = { bf2f((unsigned short)(kv.x&0xFFFFu)), bf2f((unsigned short)(kv.x>>16)),
                       bf2f((unsigned short)(kv.y&0xFFFFu)), bf2f((unsigned short)(kv.y>>16)) };
      float vvv[8]; up8(vv, vvv);
      #pragma unroll
      for (int f=0;f<4;f++)
        #pragma unroll
        for (int e=0;e<8;e++) acc[f][e] += kkv[f]*vvv[e];
    }
  }
  #pragma unroll
  for (int f=0;f<4;f++)
    #pragma unroll
    for (int e=0;e<8;e++)
      atomicAdd(&v2x[(long)b*8192 + (mg*4+f)*128 + dg*8+e], acc[f][e]);
  if (ksout){
    __syncthreads();
    float* red = (float*)klds;
    red[tid] = ksacc;
    __syncthreads();
    if (tid < 64){
      float s = red[tid]+red[64+tid]+red[128+tid]+red[192+tid];
      atomicAdd(ksout + b*64 + tid, s);
    }
  }
}

// ---------- v2t[b][n][m]: n<128: v2x[m][n]; n=128: ksum[m]; n>128: 0 -------
__global__ void k_v2cvt(char* __restrict__ wsb){
  int idx = blockIdx.x*256 + threadIdx.x;          // 36864
  if (idx >= 36864) return;
  int b = idx / 9216, rem = idx % 9216;
  int n = rem / 64, m = rem % 64;
  const float* v2f = (const float*)(wsb + V2FB);
  const float* ks  = (const float*)(wsb + KSB);
  float v = (n < 128) ? v2f[b*8192 + m*128 + n] : ((n==128) ? ks[b*64+m] : 0.f);
  ((unsigned short*)(wsb + V2TB))[b*9216 + n*64 + m] = f2bf(v);
}

// ---------- fused: attn0 + residual(h0) + LN0 -> h1 ; GLU1(h1) -> v --------
__global__ __launch_bounds__(256) void k_attnglu(
  char* __restrict__ wsb, const float* __restrict__ g0,
  const float* __restrict__ bt0, const unsigned short* __restrict__ wbf1,
  const float* __restrict__ bi1, const float* __restrict__ bo1)
{
  __shared__ unsigned short ht[64][132];
  const int b = blockIdx.y;
  const int tid = threadIdx.x;
  const int lane = tid & 63;
  const int w  = tid >> 6;
  const int c  = lane & 15;
  const int kg = lane >> 4;
  const long r0blk = (long)blockIdx.x*64;
  const long r0w = r0blk + w*16;
  // ---- attention MFMA ----
  const unsigned short* v2t = (const unsigned short*)(wsb + V2TB) + b*9216;
  short8_t aq0, aq1;
  if (r0w + c < NN){
    const unsigned short* qrow = (const unsigned short*)(wsb + QB) + ((long)b*NN + r0w + c)*64 + kg*8;
    aq0 = *(const short8_t*)qrow; aq1 = *(const short8_t*)(qrow + 32);
  } else {
    aq0 = (short8_t){0,0,0,0,0,0,0,0}; aq1 = aq0;
  }
  f32x4 acc[9];
  #pragma unroll
  for (int f=0;f<9;f++) acc[f] = (f32x4){0.f,0.f,0.f,0.f};
  #pragma unroll
  for (int f=0;f<9;f++){
    short8_t b0 = *(const short8_t*)(v2t + (f*16 + c)*64 + kg*8);
    acc[f] = __builtin_amdgcn_mfma_f32_16x16x32_bf16(aq0, b0, acc[f], 0, 0, 0);
    short8_t b1v = *(const short8_t*)(v2t + (f*16 + c)*64 + 32 + kg*8);
    acc[f] = __builtin_amdgcn_mfma_f32_16x16x32_bf16(aq1, b1v, acc[f], 0, 0, 0);
  }
  float inv[4];
  #pragma unroll
  for (int j=0;j<4;j++) inv[j] = 1.0f / __shfl(acc[8][j], (lane & 48));
  #pragma unroll
  for (int f=0;f<8;f++)
    #pragma unroll
    for (int j=0;j<4;j++)
      ht[w*16 + kg*4 + j][f*16 + c] = f2bf(acc[f][j]*inv[j]);
  __syncthreads();
  // ---- row-owner: residual + LN0 -> h1 (global + LDS) ----
  {
    int row = tid>>2, q3 = tid&3;
    long gr = r0blk + row;
    float tv[32];
    {
      const uint4* os = (const uint4*)&ht[row][q3*32];
      uint4 o0=os[0],o1=os[1],o2=os[2],o3=os[3];
      up8(o0,tv); up8(o1,tv+8); up8(o2,tv+16); up8(o3,tv+24);
    }
    if (gr < NN){
      const uint4* hs = (const uint4*)((const unsigned short*)(wsb + H0B) + ((long)b*NN + gr)*128 + q3*32);
      uint4 h0=hs[0],h1_=hs[1],h2=hs[2],h3=hs[3];
      float hv[32];
      up8(h0,hv); up8(h1_,hv+8); up8(h2,hv+16); up8(h3,hv+24);
      #pragma unroll
      for (int i=0;i<32;i++) tv[i] += hv[i];
    }
    float s = 0.f;
    #pragma unroll
    for (int i=0;i<32;i++) s += tv[i];
    s += __shfl_xor(s, 1); s += __shfl_xor(s, 2);
    float mu = s * (1.0f/128.0f);
    float vv = 0.f;
    #pragma unroll
    for (int i=0;i<32;i++){ float e = tv[i]-mu; vv += e*e; }
    vv += __shfl_xor(vv, 1); vv += __shfl_xor(vv, 2);
    float rs = rsqrtf(vv * (1.0f/128.0f) + 1e-5f);
    const float4* gp = (const float4*)(g0 + q3*32);
    const float4* bp = (const float4*)(bt0 + q3*32);
    float h1v[32];
    #pragma unroll
    for (int i8=0;i8<8;i8++){
      float4 g4 = gp[i8], b4 = bp[i8];
      h1v[i8*4  ] = (tv[i8*4  ]-mu)*rs*g4.x + b4.x;
      h1v[i8*4+1] = (tv[i8*4+1]-mu)*rs*g4.y + b4.y;
      h1v[i8*4+2] = (tv[i8*4+2]-mu)*rs*g4.z + b4.z;
      h1v[i8*4+3] = (tv[i8*4+3]-mu)*rs*g4.w + b4.w;
    }
    uint4 p0=pk8(h1v), p1=pk8(h1v+8), p2=pk8(h1v+16), p3=pk8(h1v+24);
    if (gr < NN){
      uint4* dst = (uint4*)((unsigned short*)(wsb + H1B) + ((long)b*NN + gr)*128 + q3*32);
      dst[0]=p0; dst[1]=p1; dst[2]=p2; dst[3]=p3;
    }
    uint4* d = (uint4*)&ht[row][q3*32];
    d[0]=p0; d[1]=p1; d[2]=p2; d[3]=p3;
  }
  __syncthreads();
  // ---- GLU1 MFMA from ht ----
  f32x4 gacc[16];
  #pragma unroll
  for (int f=0;f<16;f++) gacc[f] = (f32x4){0.f,0.f,0.f,0.f};
  #pragma unroll
  for (int ks=0;ks<4;ks++){
    short8_t a = *(const short8_t*)&ht[w*16 + c][ks*32 + kg*8];
    #pragma unroll
    for (int f=0;f<16;f++){
      short8_t bb = *(const short8_t*)(wbf1 + (f*16 + c)*128 + ks*32 + kg*8);
      gacc[f] = __builtin_amdgcn_mfma_f32_16x16x32_bf16(a, bb, gacc[f], 0, 0, 0);
    }
  }
  float bi_l[8], bo_l[8];
  #pragma unroll
  for (int f=0;f<8;f++){ bi_l[f] = bi1[f*16+c]; bo_l[f] = bo1[f*16+c]; }
  float ov[8][4];
  #pragma unroll
  for (int f=0;f<8;f++)
    #pragma unroll
    for (int j=0;j<4;j++){
      float a  = gacc[f][j]   + bi_l[f];
      float cc = gacc[f+8][j] + bo_l[f];
      ov[f][j] = cc / (1.0f + __expf(-a));
    }
  __syncthreads();   // WAR before overwriting ht with v
  #pragma unroll
  for (int f=0;f<8;f++)
    #pragma unroll
    for (int j=0;j<4;j++)
      ht[w*16 + kg*4 + j][f*16 + c] = f2bf(ov[f][j]);
  __syncthreads();
  {
    int row = tid>>2, q3 = tid&3;
    long gr = r0blk + row;
    if (gr < NN){
      const uint4* s = (const uint4*)&ht[row][q3*32];
      uint4 o0=s[0],o1=s[1],o2=s[2],o3=s[3];
      uint4* dst = (uint4*)((unsigned short*)(wsb + VTB) + ((long)b*NN + gr)*128 + q3*32);
      dst[0]=o0; dst[1]=o1; dst[2]=o2; dst[3]=o3;
    }
  }
}

// ---------- attn1 + residual(h1) + LN1 + MFMA regression head --------------
__global__ __launch_bounds__(256) void k_attnhead(
  char* __restrict__ wsb, const float* __restrict__ g1,
  const float* __restrict__ bt1, const float* __restrict__ b_reg,
  float* __restrict__ out)
{
  __shared__ unsigned short ht[64][132];
  const int b = blockIdx.y;
  const int tid = threadIdx.x;
  const int lane = tid & 63;
  const int w  = tid >> 6;
  const int c  = lane & 15;
  const int kg = lane >> 4;
  const long r0blk = (long)blockIdx.x*64;
  const long r0w = r0blk + w*16;
  // ---- attention MFMA ----
  const unsigned short* v2t = (const unsigned short*)(wsb + V2TB) + b*9216;
  short8_t aq0, aq1;
  if (r0w + c < NN){
    const unsigned short* qrow = (const unsigned short*)(wsb + QB) + ((long)b*NN + r0w + c)*64 + kg*8;
    aq0 = *(const short8_t*)qrow; aq1 = *(const short8_t*)(qrow + 32);
  } else {
    aq0 = (short8_t){0,0,0,0,0,0,0,0}; aq1 = aq0;
  }
  f32x4 acc[9];
  #pragma unroll
  for (int f=0;f<9;f++) acc[f] = (f32x4){0.f,0.f,0.f,0.f};
  #pragma unroll
  for (int f=0;f<9;f++){
    short8_t b0 = *(const short8_t*)(v2t + (f*16 + c)*64 + kg*8);
    acc[f] = __builtin_amdgcn_mfma_f32_16x16x32_bf16(aq0, b0, acc[f], 0, 0, 0);
    short8_t b1v = *(const short8_t*)(v2t + (f*16 + c)*64 + 32 + kg*8);
    acc[f] = __builtin_amdgcn_mfma_f32_16x16x32_bf16(aq1, b1v, acc[f], 0, 0, 0);
  }
  float inv[4];
  #pragma unroll
  for (int j=0;j<4;j++) inv[j] = 1.0f / __shfl(acc[8][j], (lane & 48));
  #pragma unroll
  for (int f=0;f<8;f++)
    #pragma unroll
    for (int j=0;j<4;j++)
      ht[w*16 + kg*4 + j][f*16 + c] = f2bf(acc[f][j]*inv[j]);
  __syncthreads();
  // ---- row-owner: residual(h1) + LN1 + relu -> h2relu (LDS) ----
  {
    int row = tid>>2, q3 = tid&3;
    long gr = r0blk + row;
    float tv[32];
    {
      const uint4* os = (const uint4*)&ht[row][q3*32];
      uint4 o0=os[0],o1=os[1],o2=os[2],o3=os[3];
      up8(o0,tv); up8(o1,tv+8); up8(o2,tv+16); up8(o3,tv+24);
    }
    if (gr < NN){
      const uint4* hs = (const uint4*)((const unsigned short*)(wsb + H1B) + ((long)b*NN + gr)*128 + q3*32);
      uint4 h0=hs[0],h1_=hs[1],h2=hs[2],h3=hs[3];
      float hv[32];
      up8(h0,hv); up8(h1_,hv+8); up8(h2,hv+16); up8(h3,hv+24);
      #pragma unroll
      for (int i=0;i<32;i++) tv[i] += hv[i];
    }
    float s = 0.f;
    #pragma unroll
    for (int i=0;i<32;i++) s += tv[i];
    s += __shfl_xor(s, 1); s += __shfl_xor(s, 2);
    float mu = s * (1.0f/128.0f);
    float vv = 0.f;
    #pragma unroll
    for (int i=0;i<32;i++){ float e = tv[i]-mu; vv += e*e; }
    vv += __shfl_xor(vv, 1); vv += __shfl_xor(vv, 2);
    float rs = rsqrtf(vv * (1.0f/128.0f) + 1e-5f);
    const float4* gp = (const float4*)(g1 + q3*32);
    const float4* bp = (const float4*)(bt1 + q3*32);
    float h2v[32];
    #pragma unroll
    for (int i8=0;i8<8;i8++){
      float4 g4 = gp[i8], b4 = bp[i8];
      h2v[i8*4  ] = fmaxf((tv[i8*4  ]-mu)*rs*g4.x + b4.x, 0.f);
      h2v[i8*4+1] = fmaxf((tv[i8*4+1]-mu)*rs*g4.y + b4.y, 0.f);
      h2v[i8*4+2] = fmaxf((tv[i8*4+2]-mu)*rs*g4.z + b4.z, 0.f);
      h2v[i8*4+3] = fmaxf((tv[i8*4+3]-mu)*rs*g4.w + b4.w, 0.f);
    }
    uint4 p0=pk8(h2v), p1=pk8(h2v+8), p2=pk8(h2v+16), p3=pk8(h2v+24);
    uint4* d = (uint4*)&ht[row][q3*32];
    d[0]=p0; d[1]=p1; d[2]=p2; d[3]=p3;
  }
  __syncthreads();
  // ---- MFMA head: y = relu([h0,h2]) @ W_regT^T + b_reg ----
  const unsigned short* wregT = (const unsigned short*)(wsb + W12B) + 8192;
  const unsigned short* h0g = (const unsigned short*)(wsb + H0B);
  f32x4 hacc = (f32x4){0.f,0.f,0.f,0.f};
  #pragma unroll
  for (int ks=0;ks<8;ks++){
    short8_t a;
    if (ks < 4){
      if (r0w + c < NN)
        a = relu8(*(const short8_t*)(h0g + ((long)b*NN + r0w + c)*128 + ks*32 + kg*8));
      else
        a = (short8_t){0,0,0,0,0,0,0,0};
    } else {
      a = *(const short8_t*)&ht[w*16 + c][(ks-4)*32 + kg*8];
    }
    short8_t bb = *(const short8_t*)(wregT + c*256 + ks*32 + kg*8);
    hacc = __builtin_amdgcn_mfma_f32_16x16x32_bf16(a, bb, hacc, 0, 0, 0);
  }
  if (c < 12){
    float br = b_reg[c];
    #pragma unroll
    for (int j=0;j<4;j++){
      long gr = r0w + kg*4 + j;
      if (gr < NN)
        out[((long)b*12 + c)*NN + gr] = hacc[j] + br;
    }
  }
}

extern "C" void kernel_launch(void* const* d_in, const int* in_sizes, int n_in,
                              void* d_out, int out_size, void* d_ws, size_t ws_size,
                              hipStream_t stream)
{
  const float* x        = (const float*)d_in[0];
  const float* node_emb = (const float*)d_in[1];
  const float* time_emb = (const float*)d_in[2];
  const float* week_emb = (const float*)d_in[3];
  const float* W_in     = (const float*)d_in[4];
  const float* b_in     = (const float*)d_in[5];
  const float* W1       = (const float*)d_in[6];
  const float* b1       = (const float*)d_in[7];
  const float* W2       = (const float*)d_in[8];
  const float* b2       = (const float*)d_in[9];
  const float* W_reg    = (const float*)d_in[10];
  const float* b_reg    = (const float*)d_in[11];
  const float* proj     = (const float*)d_in[12];
  const float* fc_in0_w = (const float*)d_in[13];
  const float* fc_in0_b = (const float*)d_in[14];
  const float* fc_out0_w= (const float*)d_in[15];
  const float* fc_out0_b= (const float*)d_in[16];
  const float* ln0_g    = (const float*)d_in[17];
  const float* ln0_b    = (const float*)d_in[18];
  const float* fc_in1_w = (const float*)d_in[19];
  const float* fc_in1_b = (const float*)d_in[20];
  const float* fc_out1_w= (const float*)d_in[21];
  const float* fc_out1_b= (const float*)d_in[22];
  const float* ln1_g    = (const float*)d_in[23];
  const float* ln1_b    = (const float*)d_in[24];
  char* wsb  = (char*)d_ws;
  float* out = (float*)d_out;

  dim3 rowgrid((NN+255)/256, NB);     // (196, 4)
  dim3 redgrid((NN+511)/512, NB);     // (98, 4)
  dim3 glugrid(3125);                 // 3125*64 = 200000 rows
  dim3 atngrid(782, NB);              // 782*64 = 50048 >= NN

  k_init0 <<<1, 256, 0, stream>>>(wsb);
  k_wcvt  <<<256, 256, 0, stream>>>(fc_in0_w, fc_out0_w, fc_in1_w, fc_out1_w, wsb);
  k_wcvt2 <<<48, 256, 0, stream>>>(W1, W2, proj, W_reg, wsb);
  k_pass1a<<<rowgrid, 256, 0, stream>>>(x, node_emb, time_emb, week_emb,
                                        W_in, b_in, wsb);
  k_pass1b<<<atngrid, 256, 0, stream>>>(b1, b2, wsb);
  k_kfin  <<<rowgrid, 256, 0, stream>>>(wsb);
  k_glu   <<<glugrid, 256, 0, stream>>>((const unsigned short*)(wsb + H0B),
                                        (const unsigned short*)(wsb + WBFB),
                                        fc_in0_b, fc_out0_b,
                                        (unsigned short*)(wsb + VTB));
  k_initv2<<<128, 256, 0, stream>>>(wsb);
  k_reduce<<<redgrid, 256, 0, stream>>>(wsb, (const unsigned short*)(wsb + VTB),
                                        (float*)(wsb + V2FB), (float*)(wsb + KSB));
  k_v2cvt <<<144, 256, 0, stream>>>(wsb);
  k_attnglu<<<atngrid, 256, 0, stream>>>(wsb, ln0_g, ln0_b,
                                         (const unsigned short*)(wsb + WBFB) + 32768,
                                         fc_in1_b, fc_out1_b);
  k_initv2<<<128, 256, 0, stream>>>(wsb);
  k_reduce<<<redgrid, 256, 0, stream>>>(wsb, (const unsigned short*)(wsb + VTB),
                                        (float*)(wsb + V2FB), (float*)nullptr);
  k_v2cvt <<<144, 256, 0, stream>>>(wsb);
  k_attnhead<<<atngrid, 256, 0, stream>>>(wsb, ln1_g, ln1_b, b_reg, out);
}

// Round 7
// 810.541 us; speedup vs baseline: 1.4183x; 1.0652x over previous
//
#include <hip/hip_runtime.h>

#define NB 4
#define NN 50000

// ---- workspace byte offsets (total ~205.16 MB, < proven 205.9 MB) ----
#define H0B   0L
#define H1B   51200000L
#define VTB   102400000L     // v (GLU out, bf16); before GLU0 doubles as RM
#define RMB   102400000L     // fp32 rm [4*50000]  (consumed by k_kfin, pre-GLU0)
#define QB    153600000L
#define KKB   179200000L
#define WBFB  204800000L     // bf16 GLU weights: layer0 [256][128], layer1 at +65536B
#define V2FB  204931072L     // fp32 v2x [4][64][128]
#define V2TB  205062144L     // bf16 v2x^T+ksum [4][144][64]
#define KSB   205135872L     // fp32 ksum [4][64]
#define GMB   205136896L     // 4 uints
#define W12B  205137920L     // bf16: W1 [32][96], W2 [32][96], proj [64][32], W_regT [16][256]

typedef short short8_t __attribute__((ext_vector_type(8)));
typedef float f32x4 __attribute__((ext_vector_type(4)));

__device__ __forceinline__ unsigned short f2bf(float f){
  unsigned u = __float_as_uint(f);
  return (unsigned short)((u + 0x7FFFu + ((u>>16)&1u)) >> 16);
}
__device__ __forceinline__ float bf2f(unsigned short s){
  return __uint_as_float(((unsigned)s)<<16);
}
__device__ __forceinline__ unsigned pk2(float a, float b){
  return (unsigned)f2bf(a) | ((unsigned)f2bf(b)<<16);
}
__device__ __forceinline__ uint4 pk8(const float* f){
  uint4 o; o.x=pk2(f[0],f[1]); o.y=pk2(f[2],f[3]);
  o.z=pk2(f[4],f[5]); o.w=pk2(f[6],f[7]); return o;
}
__device__ __forceinline__ void up8(uint4 v, float* f){
  f[0]=bf2f((unsigned short)(v.x&0xFFFFu)); f[1]=bf2f((unsigned short)(v.x>>16));
  f[2]=bf2f((unsigned short)(v.y&0xFFFFu)); f[3]=bf2f((unsigned short)(v.y>>16));
  f[4]=bf2f((unsigned short)(v.z&0xFFFFu)); f[5]=bf2f((unsigned short)(v.z>>16));
  f[6]=bf2f((unsigned short)(v.w&0xFFFFu)); f[7]=bf2f((unsigned short)(v.w>>16));
}
__device__ __forceinline__ short8_t relu8(short8_t s){
  short8_t r;
  #pragma unroll
  for (int i=0;i<8;i++){ short v = s[i]; r[i] = (v & (short)0x8000) ? (short)0 : v; }
  return r;
}
__device__ __forceinline__ unsigned encOrd(float f){
  unsigned u = __float_as_uint(f);
  return (u & 0x80000000u) ? ~u : (u | 0x80000000u);
}
__device__ __forceinline__ float decOrd(unsigned u){
  return (u & 0x80000000u) ? __uint_as_float(u & 0x7fffffffu)
                           : __uint_as_float(~u);
}

// ---- zero ksum + gmax ----
__global__ void k_init0(char* __restrict__ wsb){
  int t = threadIdx.x;
  ((float*)(wsb + KSB))[t] = 0.0f;
  if (t < 4) ((unsigned*)(wsb + GMB))[t] = 0u;
}
// ---- zero v2x fp32 ----
__global__ void k_initv2(char* __restrict__ wsb){
  int i = blockIdx.x*256 + threadIdx.x;
  if (i < 32768) ((float*)(wsb + V2FB))[i] = 0.0f;
}
// ---- GLU weights -> bf16 [n][k] ----
__global__ void k_wcvt(const float* __restrict__ wi0, const float* __restrict__ wo0,
                       const float* __restrict__ wi1, const float* __restrict__ wo1,
                       char* __restrict__ wsb){
  int idx = blockIdx.x*256 + threadIdx.x;
  if (idx >= 65536) return;
  int l = idx >> 15, r = (idx >> 7) & 255, c = idx & 127;
  const float* src = (l==0) ? ((r<128)? wi0 : wo0) : ((r<128)? wi1 : wo1);
  float v = src[(r&127)*128 + c];
  ((unsigned short*)(wsb + WBFB))[l*32768 + r*128 + c] = f2bf(v);
}
// ---- W1,W2 [32][96], proj [64][32], W_regT [16][256] -> bf16 --------------
__global__ void k_wcvt2(const float* __restrict__ W1, const float* __restrict__ W2,
                        const float* __restrict__ proj, const float* __restrict__ W_reg,
                        char* __restrict__ wsb){
  int i = blockIdx.x*256 + threadIdx.x;          // 12288 total
  if (i >= 12288) return;
  unsigned short* dst = (unsigned short*)(wsb + W12B);
  float v;
  if (i < 3072) v = W1[i];
  else if (i < 6144) v = W2[i-3072];
  else if (i < 8192) v = proj[i-6144];
  else {
    int r = (i-8192) >> 8, c = (i-8192) & 255;
    v = (r < 12) ? W_reg[r*256 + c] : 0.f;
  }
  dst[i] = f2bf(v);
}

// ---------- pass1a: h0 (W_in matmul + embeddings) --------------------------
__global__ __launch_bounds__(256) void k_pass1a(
  const float* __restrict__ x, const float* __restrict__ node_emb,
  const float* __restrict__ time_emb, const float* __restrict__ week_emb,
  const float* __restrict__ W_in, const float* __restrict__ b_in,
  char* __restrict__ wsb)
{
  const int b = blockIdx.y;
  const int n = blockIdx.x*256 + threadIdx.x;
  if (n >= NN) return;
  const long row = (long)b*NN + n;
  float xr[36];
  {
    const float4* xp = (const float4*)(x + row*36);
    #pragma unroll
    for (int i=0;i<9;i++){ float4 t=xp[i]; xr[4*i]=t.x; xr[4*i+1]=t.y; xr[4*i+2]=t.z; xr[4*i+3]=t.w; }
  }
  int tidx = (int)(xr[34]*288.0f); tidx = tidx<0?0:(tidx>287?287:tidx);
  int widx = (int)(xr[35]);        widx = widx<0?0:(widx>6?6:widx);
  uint4* h0q = (uint4*)(wsb + H0B) + row*16;
  float hh[32];
  #pragma unroll 1
  for (int jj=0;jj<8;jj++){
    #pragma unroll
    for (int jl=0;jl<4;jl++){
      const int j = jj*4+jl;
      const float* w = W_in + j*36;
      float a0=0.f,a1=0.f,a2=0.f,a3=0.f;
      #pragma unroll
      for (int i=0;i<36;i+=4){ a0+=xr[i]*w[i]; a1+=xr[i+1]*w[i+1]; a2+=xr[i+2]*w[i+2]; a3+=xr[i+3]*w[i+3]; }
      hh[j] = b_in[j] + ((a0+a1)+(a2+a3));
    }
  }
  #pragma unroll
  for (int c=0;c<4;c++) h0q[c] = pk8(hh + 8*c);
  float xg[96];
  {
    const float4* p0 = (const float4*)(node_emb + (long)n*32);
    const float4* p1 = (const float4*)(time_emb + (long)tidx*32);
    const float4* p2 = (const float4*)(week_emb + (long)widx*32);
    #pragma unroll
    for (int i=0;i<8;i++){ float4 t=p0[i]; xg[4*i]=t.x; xg[4*i+1]=t.y; xg[4*i+2]=t.z; xg[4*i+3]=t.w; }
    #pragma unroll
    for (int i=0;i<8;i++){ float4 t=p1[i]; xg[32+4*i]=t.x; xg[32+4*i+1]=t.y; xg[32+4*i+2]=t.z; xg[32+4*i+3]=t.w; }
    #pragma unroll
    for (int i=0;i<8;i++){ float4 t=p2[i]; xg[64+4*i]=t.x; xg[64+4*i+1]=t.y; xg[64+4*i+2]=t.z; xg[64+4*i+3]=t.w; }
  }
  #pragma unroll
  for (int c=0;c<12;c++) h0q[4+c] = pk8(xg + 8*c);
}

// ---------- pass1b (MFMA): q, k', rm, global key max -----------------------
__global__ __launch_bounds__(256) void k_pass1b(
  const float* __restrict__ b1, const float* __restrict__ b2,
  char* __restrict__ wsb)
{
  __shared__ unsigned short xgt[64][96];
  __shared__ unsigned short dt[2][64][32];
  __shared__ unsigned short ot[64][64];
  __shared__ float wred[4];
  const int b   = blockIdx.y;
  const int tid = threadIdx.x;
  const int lane= tid & 63;
  const int w   = tid >> 6;
  const int c   = lane & 15;
  const int kg  = lane >> 4;
  const long r0blk = (long)blockIdx.x * 64;
  {
    int row = tid >> 2, q3 = tid & 3;
    long gr = r0blk + row;
    uint4 v0={0,0,0,0}, v1=v0, v2=v0;
    if (gr < NN){
      // xg = h0 row cols 32..127 (byte offset 64 within 256B row)
      const uint4* src = (const uint4*)(wsb + H0B + ((long)b*NN + gr)*256 + 64 + q3*48);
      v0=src[0]; v1=src[1]; v2=src[2];
    }
    uint4* d = (uint4*)&xgt[row][q3*24];
    d[0]=v0; d[1]=v1; d[2]=v2;
  }
  __syncthreads();
  const unsigned short* w1bf = (const unsigned short*)(wsb + W12B);
  const unsigned short* w2bf = w1bf + 3072;
  const unsigned short* pjbf = w1bf + 6144;
  f32x4 accd[2][2];
  #pragma unroll
  for (int s=0;s<2;s++)
    #pragma unroll
    for (int f=0;f<2;f++) accd[s][f] = (f32x4){0.f,0.f,0.f,0.f};
  #pragma unroll
  for (int ks=0;ks<3;ks++){
    short8_t a = *(const short8_t*)&xgt[w*16 + c][ks*32 + kg*8];
    #pragma unroll
    for (int f=0;f<2;f++){
      short8_t bw1 = *(const short8_t*)(w1bf + (f*16+c)*96 + ks*32 + kg*8);
      accd[0][f] = __builtin_amdgcn_mfma_f32_16x16x32_bf16(a, bw1, accd[0][f], 0,0,0);
      short8_t bw2 = *(const short8_t*)(w2bf + (f*16+c)*96 + ks*32 + kg*8);
      accd[1][f] = __builtin_amdgcn_mfma_f32_16x16x32_bf16(a, bw2, accd[1][f], 0,0,0);
    }
  }
  const float DSC = 0.42044820762685725f;   // 32^-0.25
  float dv[2][2][4];
  #pragma unroll
  for (int f=0;f<2;f++){
    float bb1 = b1[f*16+c], bb2 = b2[f*16+c];
    #pragma unroll
    for (int jj=0;jj<4;jj++){
      dv[0][f][jj] = (accd[0][f][jj] + bb1) * DSC;
      dv[1][f][jj] = (accd[1][f][jj] + bb2) * DSC;
    }
  }
  float dg[2][4];
  #pragma unroll
  for (int s=0;s<2;s++)
    #pragma unroll
    for (int jj=0;jj<4;jj++){
      float t = dv[s][0][jj]*dv[s][0][jj] + dv[s][1][jj]*dv[s][1][jj];
      #pragma unroll
      for (int off=1; off<16; off<<=1) t += __shfl_xor(t, off);
      dg[s][jj] = 0.5f * t;
    }
  #pragma unroll
  for (int s=0;s<2;s++)
    #pragma unroll
    for (int f=0;f<2;f++)
      #pragma unroll
      for (int jj=0;jj<4;jj++)
        dt[s][w*16 + kg*4 + jj][f*16 + c] = f2bf(dv[s][f][jj]);
  __syncthreads();
  f32x4 acc2[2][4];
  #pragma unroll
  for (int s=0;s<2;s++){
    short8_t ad = *(const short8_t*)&dt[s][w*16 + c][kg*8];
    #pragma unroll
    for (int f=0;f<4;f++){
      short8_t bp = *(const short8_t*)(pjbf + (f*16+c)*32 + kg*8);
      acc2[s][f] = __builtin_amdgcn_mfma_f32_16x16x32_bf16(ad, bp, (f32x4){0.f,0.f,0.f,0.f}, 0,0,0);
    }
  }
  float mx[2][4];
  #pragma unroll
  for (int s=0;s<2;s++)
    #pragma unroll
    for (int jj=0;jj<4;jj++){
      float t = fmaxf(fmaxf(acc2[s][0][jj],acc2[s][1][jj]),
                      fmaxf(acc2[s][2][jj],acc2[s][3][jj]));
      #pragma unroll
      for (int off=1; off<16; off<<=1) t = fmaxf(t, __shfl_xor(t, off));
      mx[s][jj] = t;
    }
  #pragma unroll
  for (int f=0;f<4;f++)
    #pragma unroll
    for (int jj=0;jj<4;jj++){
      float qv = 0.125f*(__expf(acc2[0][f][jj] - dg[0][jj] - mx[0][jj]) + 1e-6f);
      ot[w*16 + kg*4 + jj][f*16 + c] = f2bf(qv);
    }
  __syncthreads();
  {
    int row = tid >> 2, q3 = tid & 3;
    long gr = r0blk + row;
    if (gr < NN){
      const uint4* s = (const uint4*)&ot[row][q3*16];
      uint4* dst = (uint4*)((unsigned short*)(wsb + QB) + ((long)b*NN + gr)*64 + q3*16);
      dst[0] = s[0]; dst[1] = s[1];
    }
  }
  __syncthreads();
  float bmax = -3.0e38f;
  #pragma unroll
  for (int f=0;f<4;f++)
    #pragma unroll
    for (int jj=0;jj<4;jj++){
      float kv = __expf(acc2[1][f][jj] - mx[1][jj]);
      ot[w*16 + kg*4 + jj][f*16 + c] = f2bf(kv);
    }
  #pragma unroll
  for (int jj=0;jj<4;jj++){
    long gr = r0blk + w*16 + kg*4 + jj;
    bool val = (gr < NN);
    if (val && c==0)
      ((float*)(wsb + RMB))[(long)b*NN + gr] = mx[1][jj] - dg[1][jj];
    if (val) bmax = fmaxf(bmax, mx[1][jj]);
  }
  #pragma unroll
  for (int off=32; off>0; off>>=1) bmax = fmaxf(bmax, __shfl_xor(bmax, off));
  if (lane==0) wred[w] = bmax;
  __syncthreads();
  {
    int row = tid >> 2, q3 = tid & 3;
    long gr = r0blk + row;
    if (gr < NN){
      const uint4* s = (const uint4*)&ot[row][q3*16];
      uint4* dst = (uint4*)((unsigned short*)(wsb + KKB) + ((long)b*NN + gr)*64 + q3*16);
      dst[0] = s[0]; dst[1] = s[1];
    }
  }
  if (tid==0){
    float m2 = fmaxf(fmaxf(wred[0],wred[1]), fmaxf(wred[2],wred[3]));
    atomicMax((unsigned*)(wsb + GMB) + b, encOrd(m2));
  }
}

// ---------- finalize k = 0.125*(k'*exp(rm-gmax)+1e-6) ----------------------
__global__ __launch_bounds__(256) void k_kfin(char* __restrict__ wsb){
  const int b = blockIdx.y;
  const int n = blockIdx.x*256 + threadIdx.x;
  if (n >= NN) return;
  const long row = (long)b*NN + n;
  const float gm = decOrd(((const unsigned*)(wsb + GMB))[b]);
  const float scale = __expf(((const float*)(wsb + RMB))[row] - gm);
  uint4* kq = (uint4*)(wsb + KKB) + row*8;
  #pragma unroll
  for (int mm=0;mm<8;mm++){
    float t[8]; up8(kq[mm], t);
    #pragma unroll
    for (int e=0;e<8;e++) t[e] = 0.125f*(t[e]*scale + 1e-6f);
    kq[mm] = pk8(t);
  }
}

// ---------- MFMA GLU (layer 0) with LDS-staged output ----------------------
__global__ __launch_bounds__(256) void k_glu(
  const unsigned short* __restrict__ h, const unsigned short* __restrict__ wbf,
  const float* __restrict__ bi, const float* __restrict__ bo,
  unsigned short* __restrict__ vout)
{
  __shared__ unsigned short vt[64][132];
  const int tid = threadIdx.x;
  const int lane = tid & 63;
  const int wid  = tid >> 6;
  const int c  = lane & 15;
  const int kg = lane >> 4;
  const long r0blk = (long)blockIdx.x*64;
  const unsigned short* arow = h + (r0blk + wid*16 + c)*128 + kg*8;
  f32x4 acc[16];
  #pragma unroll
  for (int f=0;f<16;f++) acc[f] = (f32x4){0.f,0.f,0.f,0.f};
  #pragma unroll
  for (int ks=0;ks<4;ks++){
    short8_t a = *(const short8_t*)(arow + ks*32);
    #pragma unroll
    for (int f=0;f<16;f++){
      short8_t bb = *(const short8_t*)(wbf + (f*16 + c)*128 + ks*32 + kg*8);
      acc[f] = __builtin_amdgcn_mfma_f32_16x16x32_bf16(a, bb, acc[f], 0, 0, 0);
    }
  }
  float bi_l[8], bo_l[8];
  #pragma unroll
  for (int f=0;f<8;f++){ bi_l[f] = bi[f*16+c]; bo_l[f] = bo[f*16+c]; }
  #pragma unroll
  for (int f=0;f<8;f++){
    #pragma unroll
    for (int j=0;j<4;j++){
      float a  = acc[f][j]   + bi_l[f];
      float cc = acc[f+8][j] + bo_l[f];
      float o  = cc / (1.0f + __expf(-a));
      vt[wid*16 + kg*4 + j][f*16 + c] = f2bf(o);
    }
  }
  __syncthreads();
  {
    int row = tid>>2, q = tid&3;
    const uint4* s = (const uint4*)&vt[row][q*32];
    uint4 o0=s[0],o1=s[1],o2=s[2],o3=s[3];
    uint4* dst = (uint4*)(vout + (r0blk + row)*128 + q*32);
    dst[0]=o0; dst[1]=o1; dst[2]=o2; dst[3]=o3;
  }
}

// ---------- v2x[b][m][d] = sum_n k[n][m]*v[n][d]  (+ optional ksum) --------
__global__ __launch_bounds__(256) void k_reduce(const char* __restrict__ wsb,
                                                const unsigned short* __restrict__ vt,
                                                float* __restrict__ v2x,
                                                float* __restrict__ ksout)
{
  const int b  = blockIdx.y;
  const int r0 = blockIdx.x*512;
  __shared__ unsigned short klds[64*64];
  __shared__ unsigned short vlds[64*128];
  const int tid = threadIdx.x;
  const int mg = tid >> 4;
  const int dg = tid & 15;
  float acc[4][8];
  #pragma unroll
  for (int f=0;f<4;f++)
    #pragma unroll
    for (int e=0;e<8;e++) acc[f][e]=0.f;
  float ksacc = 0.f;
  const uint4* kbase = (const uint4*)(wsb + KKB) + (long)b*NN*8;
  const uint4* vbase = (const uint4*)vt + (long)b*NN*16;
  const int rend = min(r0+512, NN);
  for (int t0=r0; t0<rend; t0+=64){
    __syncthreads();
    #pragma unroll
    for (int e=0;e<2;e++){
      int f = tid + 256*e;
      int rr = f >> 3, cc = f & 7;
      int gr = t0 + rr;
      uint4 val = {0u,0u,0u,0u};
      if (gr < NN) val = kbase[(long)gr*8 + cc];
      ((uint4*)klds)[f] = val;
    }
    #pragma unroll
    for (int e=0;e<4;e++){
      int f = tid + 256*e;
      int rr = f >> 4, cc = f & 15;
      int gr = t0 + rr;
      uint4 val = {0u,0u,0u,0u};
      if (gr < NN) val = vbase[(long)gr*16 + cc];
      ((uint4*)vlds)[f] = val;
    }
    __syncthreads();
    if (ksout){
      for (int r = (tid>>6); r<64; r+=4) ksacc += bf2f(klds[r*64 + (tid&63)]);
    }
    #pragma unroll 2
    for (int r=0;r<64;r++){
      uint2 kv = ((const uint2*)klds)[r*16 + mg];
      uint4 vv = ((const uint4*)vlds)[r*16 + dg];
      float kkv[4] = { bf2f((unsigned short)(kv.x&0xFFFFu)), bf2f((unsigned short)(kv.x>>16)),
                       bf2f((unsigned short)(kv.y&0xFFFFu)), bf2f((unsigned short)(kv.y>>16)) };
      float vvv[8]; up8(vv, vvv);
      #pragma unroll
      for (int f=0;f<4;f++)
        #pragma unroll
        for (int e=0;e<8;e++) acc[f][e] += kkv[f]*vvv[e];
    }
  }
  #pragma unroll
  for (int f=0;f<4;f++)
    #pragma unroll
    for (int e=0;e<8;e++)
      atomicAdd(&v2x[(long)b*8192 + (mg*4+f)*128 + dg*8+e], acc[f][e]);
  if (ksout){
    __syncthreads();
    float* red = (float*)klds;
    red[tid] = ksacc;
    __syncthreads();
    if (tid < 64){
      float s = red[tid]+red[64+tid]+red[128+tid]+red[192+tid];
      atomicAdd(ksout + b*64 + tid, s);
    }
  }
}

// ---------- v2t[b][n][m]: n<128: v2x[m][n]; n=128: ksum[m]; n>128: 0 -------
__global__ void k_v2cvt(char* __restrict__ wsb){
  int idx = blockIdx.x*256 + threadIdx.x;          // 36864
  if (idx >= 36864) return;
  int b = idx / 9216, rem = idx % 9216;
  int n = rem / 64, m = rem % 64;
  const float* v2f = (const float*)(wsb + V2FB);
  const float* ks  = (const float*)(wsb + KSB);
  float v = (n < 128) ? v2f[b*8192 + m*128 + n] : ((n==128) ? ks[b*64+m] : 0.f);
  ((unsigned short*)(wsb + V2TB))[b*9216 + n*64 + m] = f2bf(v);
}

// ---------- fused: attn0 + residual(h0) + LN0 -> h1 ; GLU1(h1) -> v --------
__global__ __launch_bounds__(256) void k_attnglu(
  char* __restrict__ wsb, const float* __restrict__ g0,
  const float* __restrict__ bt0, const unsigned short* __restrict__ wbf1,
  const float* __restrict__ bi1, const float* __restrict__ bo1)
{
  __shared__ unsigned short ht[64][132];    // 16896 B
  __shared__ unsigned short v2s[144*72];    // 20736 B, padded [144][72]
  const int b = blockIdx.y;
  const int tid = threadIdx.x;
  const int lane = tid & 63;
  const int w  = tid >> 6;
  const int c  = lane & 15;
  const int kg = lane >> 4;
  const long r0blk = (long)blockIdx.x*64;
  const long r0w = r0blk + w*16;
  const int rrow = tid>>2, rq3 = tid&3;
  const long rgr = r0blk + rrow;
  // ---- early independent loads: Q frags + h0 residual slice; stage v2t ----
  short8_t aq0, aq1;
  if (r0w + c < NN){
    const unsigned short* qrow = (const unsigned short*)(wsb + QB) + ((long)b*NN + r0w + c)*64 + kg*8;
    aq0 = *(const short8_t*)qrow; aq1 = *(const short8_t*)(qrow + 32);
  } else {
    aq0 = (short8_t){0,0,0,0,0,0,0,0}; aq1 = aq0;
  }
  uint4 rh0={0,0,0,0}, rh1={0,0,0,0}, rh2={0,0,0,0}, rh3={0,0,0,0};
  if (rgr < NN){
    const uint4* hs = (const uint4*)((const unsigned short*)(wsb + H0B) + ((long)b*NN + rgr)*128 + rq3*32);
    rh0=hs[0]; rh1=hs[1]; rh2=hs[2]; rh3=hs[3];
  }
  {
    const uint4* v2g = (const uint4*)((const unsigned short*)(wsb + V2TB) + b*9216);
    #pragma unroll
    for (int e=0;e<5;e++){
      int j = tid + 256*e;
      if (j < 1152){
        int row = j >> 3, cc = j & 7;
        *(uint4*)&v2s[row*72 + cc*8] = v2g[j];
      }
    }
  }
  __syncthreads();
  // ---- attention MFMA (B from LDS) ----
  f32x4 acc[9];
  #pragma unroll
  for (int f=0;f<9;f++) acc[f] = (f32x4){0.f,0.f,0.f,0.f};
  #pragma unroll
  for (int f=0;f<9;f++){
    short8_t b0 = *(const short8_t*)&v2s[(f*16 + c)*72 + kg*8];
    acc[f] = __builtin_amdgcn_mfma_f32_16x16x32_bf16(aq0, b0, acc[f], 0, 0, 0);
    short8_t b1v = *(const short8_t*)&v2s[(f*16 + c)*72 + 32 + kg*8];
    acc[f] = __builtin_amdgcn_mfma_f32_16x16x32_bf16(aq1, b1v, acc[f], 0, 0, 0);
  }
  float inv[4];
  #pragma unroll
  for (int j=0;j<4;j++) inv[j] = 1.0f / __shfl(acc[8][j], (lane & 48));
  #pragma unroll
  for (int f=0;f<8;f++)
    #pragma unroll
    for (int j=0;j<4;j++)
      ht[w*16 + kg*4 + j][f*16 + c] = f2bf(acc[f][j]*inv[j]);
  __syncthreads();
  // ---- row-owner: residual(regs) + LN0 -> h1 (global + LDS) ----
  {
    float tv[32];
    {
      const uint4* os = (const uint4*)&ht[rrow][rq3*32];
      uint4 o0=os[0],o1=os[1],o2=os[2],o3=os[3];
      up8(o0,tv); up8(o1,tv+8); up8(o2,tv+16); up8(o3,tv+24);
    }
    {
      float hv[32];
      up8(rh0,hv); up8(rh1,hv+8); up8(rh2,hv+16); up8(rh3,hv+24);
      #pragma unroll
      for (int i=0;i<32;i++) tv[i] += hv[i];
    }
    float s = 0.f;
    #pragma unroll
    for (int i=0;i<32;i++) s += tv[i];
    s += __shfl_xor(s, 1); s += __shfl_xor(s, 2);
    float mu = s * (1.0f/128.0f);
    float vv = 0.f;
    #pragma unroll
    for (int i=0;i<32;i++){ float e = tv[i]-mu; vv += e*e; }
    vv += __shfl_xor(vv, 1); vv += __shfl_xor(vv, 2);
    float rs = rsqrtf(vv * (1.0f/128.0f) + 1e-5f);
    const float4* gp = (const float4*)(g0 + rq3*32);
    const float4* bp = (const float4*)(bt0 + rq3*32);
    float h1v[32];
    #pragma unroll
    for (int i8=0;i8<8;i8++){
      float4 g4 = gp[i8], b4 = bp[i8];
      h1v[i8*4  ] = (tv[i8*4  ]-mu)*rs*g4.x + b4.x;
      h1v[i8*4+1] = (tv[i8*4+1]-mu)*rs*g4.y + b4.y;
      h1v[i8*4+2] = (tv[i8*4+2]-mu)*rs*g4.z + b4.z;
      h1v[i8*4+3] = (tv[i8*4+3]-mu)*rs*g4.w + b4.w;
    }
    uint4 p0=pk8(h1v), p1=pk8(h1v+8), p2=pk8(h1v+16), p3=pk8(h1v+24);
    if (rgr < NN){
      uint4* dst = (uint4*)((unsigned short*)(wsb + H1B) + ((long)b*NN + rgr)*128 + rq3*32);
      dst[0]=p0; dst[1]=p1; dst[2]=p2; dst[3]=p3;
    }
    uint4* d = (uint4*)&ht[rrow][rq3*32];
    d[0]=p0; d[1]=p1; d[2]=p2; d[3]=p3;
  }
  __syncthreads();
  // ---- GLU1 MFMA from ht ----
  f32x4 gacc[16];
  #pragma unroll
  for (int f=0;f<16;f++) gacc[f] = (f32x4){0.f,0.f,0.f,0.f};
  #pragma unroll
  for (int ks=0;ks<4;ks++){
    short8_t a = *(const short8_t*)&ht[w*16 + c][ks*32 + kg*8];
    #pragma unroll
    for (int f=0;f<16;f++){
      short8_t bb = *(const short8_t*)(wbf1 + (f*16 + c)*128 + ks*32 + kg*8);
      gacc[f] = __builtin_amdgcn_mfma_f32_16x16x32_bf16(a, bb, gacc[f], 0, 0, 0);
    }
  }
  float bi_l[8], bo_l[8];
  #pragma unroll
  for (int f=0;f<8;f++){ bi_l[f] = bi1[f*16+c]; bo_l[f] = bo1[f*16+c]; }
  float ov[8][4];
  #pragma unroll
  for (int f=0;f<8;f++)
    #pragma unroll
    for (int j=0;j<4;j++){
      float a  = gacc[f][j]   + bi_l[f];
      float cc = gacc[f+8][j] + bo_l[f];
      ov[f][j] = cc / (1.0f + __expf(-a));
    }
  __syncthreads();   // WAR before overwriting ht with v
  #pragma unroll
  for (int f=0;f<8;f++)
    #pragma unroll
    for (int j=0;j<4;j++)
      ht[w*16 + kg*4 + j][f*16 + c] = f2bf(ov[f][j]);
  __syncthreads();
  {
    if (rgr < NN){
      const uint4* s = (const uint4*)&ht[rrow][rq3*32];
      uint4 o0=s[0],o1=s[1],o2=s[2],o3=s[3];
      uint4* dst = (uint4*)((unsigned short*)(wsb + VTB) + ((long)b*NN + rgr)*128 + rq3*32);
      dst[0]=o0; dst[1]=o1; dst[2]=o2; dst[3]=o3;
    }
  }
}

// ---------- attn1 + residual(h1) + LN1 + MFMA regression head --------------
__global__ __launch_bounds__(256) void k_attnhead(
  char* __restrict__ wsb, const float* __restrict__ g1,
  const float* __restrict__ bt1, const float* __restrict__ b_reg,
  float* __restrict__ out)
{
  __shared__ unsigned short ht[64][132];    // 16896 B
  __shared__ unsigned short v2s[144*72];    // 20736 B; reused as h0 tile [64][136]
  const int b = blockIdx.y;
  const int tid = threadIdx.x;
  const int lane = tid & 63;
  const int w  = tid >> 6;
  const int c  = lane & 15;
  const int kg = lane >> 4;
  const long r0blk = (long)blockIdx.x*64;
  const long r0w = r0blk + w*16;
  const int rrow = tid>>2, rq3 = tid&3;
  const long rgr = r0blk + rrow;
  // ---- early independent loads ----
  short8_t aq0, aq1;
  if (r0w + c < NN){
    const unsigned short* qrow = (const unsigned short*)(wsb + QB) + ((long)b*NN + r0w + c)*64 + kg*8;
    aq0 = *(const short8_t*)qrow; aq1 = *(const short8_t*)(qrow + 32);
  } else {
    aq0 = (short8_t){0,0,0,0,0,0,0,0}; aq1 = aq0;
  }
  uint4 rh0={0,0,0,0}, rh1={0,0,0,0}, rh2={0,0,0,0}, rh3={0,0,0,0};   // h1 residual slice
  uint4 ah0={0,0,0,0}, ah1={0,0,0,0}, ah2={0,0,0,0}, ah3={0,0,0,0};   // h0 head slice
  if (rgr < NN){
    const uint4* hs = (const uint4*)((const unsigned short*)(wsb + H1B) + ((long)b*NN + rgr)*128 + rq3*32);
    rh0=hs[0]; rh1=hs[1]; rh2=hs[2]; rh3=hs[3];
    const uint4* h0s = (const uint4*)((const unsigned short*)(wsb + H0B) + ((long)b*NN + rgr)*128 + rq3*32);
    ah0=h0s[0]; ah1=h0s[1]; ah2=h0s[2]; ah3=h0s[3];
  }
  {
    const uint4* v2g = (const uint4*)((const unsigned short*)(wsb + V2TB) + b*9216);
    #pragma unroll
    for (int e=0;e<5;e++){
      int j = tid + 256*e;
      if (j < 1152){
        int row = j >> 3, cc = j & 7;
        *(uint4*)&v2s[row*72 + cc*8] = v2g[j];
      }
    }
  }
  __syncthreads();
  // ---- attention MFMA (B from LDS) ----
  f32x4 acc[9];
  #pragma unroll
  for (int f=0;f<9;f++) acc[f] = (f32x4){0.f,0.f,0.f,0.f};
  #pragma unroll
  for (int f=0;f<9;f++){
    short8_t b0 = *(const short8_t*)&v2s[(f*16 + c)*72 + kg*8];
    acc[f] = __builtin_amdgcn_mfma_f32_16x16x32_bf16(aq0, b0, acc[f], 0, 0, 0);
    short8_t b1v = *(const short8_t*)&v2s[(f*16 + c)*72 + 32 + kg*8];
    acc[f] = __builtin_amdgcn_mfma_f32_16x16x32_bf16(aq1, b1v, acc[f], 0, 0, 0);
  }
  float inv[4];
  #pragma unroll
  for (int j=0;j<4;j++) inv[j] = 1.0f / __shfl(acc[8][j], (lane & 48));
  #pragma unroll
  for (int f=0;f<8;f++)
    #pragma unroll
    for (int j=0;j<4;j++)
      ht[w*16 + kg*4 + j][f*16 + c] = f2bf(acc[f][j]*inv[j]);
  __syncthreads();   // ht ready; v2s reads done -> safe to reuse as h0 tile
  // ---- row-owner: residual(h1 regs) + LN1 + relu -> h2relu (LDS);
  //      also park h0 slice into v2s as [64][136] tile for the head ----
  {
    unsigned short* h0t = v2s;
    uint4* hd = (uint4*)&h0t[rrow*136 + rq3*32];
    hd[0]=ah0; hd[1]=ah1; hd[2]=ah2; hd[3]=ah3;
    float tv[32];
    {
      const uint4* os = (const uint4*)&ht[rrow][rq3*32];
      uint4 o0=os[0],o1=os[1],o2=os[2],o3=os[3];
      up8(o0,tv); up8(o1,tv+8); up8(o2,tv+16); up8(o3,tv+24);
    }
    {
      float hv[32];
      up8(rh0,hv); up8(rh1,hv+8); up8(rh2,hv+16); up8(rh3,hv+24);
      #pragma unroll
      for (int i=0;i<32;i++) tv[i] += hv[i];
    }
    float s = 0.f;
    #pragma unroll
    for (int i=0;i<32;i++) s += tv[i];
    s += __shfl_xor(s, 1); s += __shfl_xor(s, 2);
    float mu = s * (1.0f/128.0f);
    float vv = 0.f;
    #pragma unroll
    for (int i=0;i<32;i++){ float e = tv[i]-mu; vv += e*e; }
    vv += __shfl_xor(vv, 1); vv += __shfl_xor(vv, 2);
    float rs = rsqrtf(vv * (1.0f/128.0f) + 1e-5f);
    const float4* gp = (const float4*)(g1 + rq3*32);
    const float4* bp = (const float4*)(bt1 + rq3*32);
    float h2v[32];
    #pragma unroll
    for (int i8=0;i8<8;i8++){
      float4 g4 = gp[i8], b4 = bp[i8];
      h2v[i8*4  ] = fmaxf((tv[i8*4  ]-mu)*rs*g4.x + b4.x, 0.f);
      h2v[i8*4+1] = fmaxf((tv[i8*4+1]-mu)*rs*g4.y + b4.y, 0.f);
      h2v[i8*4+2] = fmaxf((tv[i8*4+2]-mu)*rs*g4.z + b4.z, 0.f);
      h2v[i8*4+3] = fmaxf((tv[i8*4+3]-mu)*rs*g4.w + b4.w, 0.f);
    }
    uint4 p0=pk8(h2v), p1=pk8(h2v+8), p2=pk8(h2v+16), p3=pk8(h2v+24);
    uint4* d = (uint4*)&ht[rrow][rq3*32];
    d[0]=p0; d[1]=p1; d[2]=p2; d[3]=p3;
  }
  __syncthreads();
  // ---- MFMA head: y = relu([h0,h2]) @ W_regT^T + b_reg ----
  const unsigned short* wregT = (const unsigned short*)(wsb + W12B) + 8192;
  const unsigned short* h0t = v2s;
  f32x4 hacc = (f32x4){0.f,0.f,0.f,0.f};
  #pragma unroll
  for (int ks=0;ks<8;ks++){
    short8_t a;
    if (ks < 4)
      a = relu8(*(const short8_t*)&h0t[(w*16 + c)*136 + ks*32 + kg*8]);
    else
      a = *(const short8_t*)&ht[w*16 + c][(ks-4)*32 + kg*8];
    short8_t bb = *(const short8_t*)(wregT + c*256 + ks*32 + kg*8);
    hacc = __builtin_amdgcn_mfma_f32_16x16x32_bf16(a, bb, hacc, 0, 0, 0);
  }
  if (c < 12){
    float br = b_reg[c];
    #pragma unroll
    for (int j=0;j<4;j++){
      long gr = r0w + kg*4 + j;
      if (gr < NN)
        out[((long)b*12 + c)*NN + gr] = hacc[j] + br;
    }
  }
}

extern "C" void kernel_launch(void* const* d_in, const int* in_sizes, int n_in,
                              void* d_out, int out_size, void* d_ws, size_t ws_size,
                              hipStream_t stream)
{
  const float* x        = (const float*)d_in[0];
  const float* node_emb = (const float*)d_in[1];
  const float* time_emb = (const float*)d_in[2];
  const float* week_emb = (const float*)d_in[3];
  const float* W_in     = (const float*)d_in[4];
  const float* b_in     = (const float*)d_in[5];
  const float* W1       = (const float*)d_in[6];
  const float* b1       = (const float*)d_in[7];
  const float* W2       = (const float*)d_in[8];
  const float* b2       = (const float*)d_in[9];
  const float* W_reg    = (const float*)d_in[10];
  const float* b_reg    = (const float*)d_in[11];
  const float* proj     = (const float*)d_in[12];
  const float* fc_in0_w = (const float*)d_in[13];
  const float* fc_in0_b = (const float*)d_in[14];
  const float* fc_out0_w= (const float*)d_in[15];
  const float* fc_out0_b= (const float*)d_in[16];
  const float* ln0_g    = (const float*)d_in[17];
  const float* ln0_b    = (const float*)d_in[18];
  const float* fc_in1_w = (const float*)d_in[19];
  const float* fc_in1_b = (const float*)d_in[20];
  const float* fc_out1_w= (const float*)d_in[21];
  const float* fc_out1_b= (const float*)d_in[22];
  const float* ln1_g    = (const float*)d_in[23];
  const float* ln1_b    = (const float*)d_in[24];
  char* wsb  = (char*)d_ws;
  float* out = (float*)d_out;

  dim3 rowgrid((NN+255)/256, NB);     // (196, 4)
  dim3 redgrid((NN+511)/512, NB);     // (98, 4)
  dim3 glugrid(3125);                 // 3125*64 = 200000 rows
  dim3 atngrid(782, NB);              // 782*64 = 50048 >= NN

  k_init0 <<<1, 256, 0, stream>>>(wsb);
  k_wcvt  <<<256, 256, 0, stream>>>(fc_in0_w, fc_out0_w, fc_in1_w, fc_out1_w, wsb);
  k_wcvt2 <<<48, 256, 0, stream>>>(W1, W2, proj, W_reg, wsb);
  k_pass1a<<<rowgrid, 256, 0, stream>>>(x, node_emb, time_emb, week_emb,
                                        W_in, b_in, wsb);
  k_pass1b<<<atngrid, 256, 0, stream>>>(b1, b2, wsb);
  k_kfin  <<<rowgrid, 256, 0, stream>>>(wsb);
  k_glu   <<<glugrid, 256, 0, stream>>>((const unsigned short*)(wsb + H0B),
                                        (const unsigned short*)(wsb + WBFB),
                                        fc_in0_b, fc_out0_b,
                                        (unsigned short*)(wsb + VTB));
  k_initv2<<<128, 256, 0, stream>>>(wsb);
  k_reduce<<<redgrid, 256, 0, stream>>>(wsb, (const unsigned short*)(wsb + VTB),
                                        (float*)(wsb + V2FB), (float*)(wsb + KSB));
  k_v2cvt <<<144, 256, 0, stream>>>(wsb);
  k_attnglu<<<atngrid, 256, 0, stream>>>(wsb, ln0_g, ln0_b,
                                         (const unsigned short*)(wsb + WBFB) + 32768,
                                         fc_in1_b, fc_out1_b);
  k_initv2<<<128, 256, 0, stream>>>(wsb);
  k_reduce<<<redgrid, 256, 0, stream>>>(wsb, (const unsigned short*)(wsb + VTB),
                                        (float*)(wsb + V2FB), (float*)nullptr);
  k_v2cvt <<<144, 256, 0, stream>>>(wsb);
  k_attnhead<<<atngrid, 256, 0, stream>>>(wsb, ln1_g, ln1_b, b_reg, out);
}

// Round 8
// 517.687 us; speedup vs baseline: 2.2206x; 1.5657x over previous
//
#include <hip/hip_runtime.h>

#define NB 4
#define NN 50000

// ---- workspace byte offsets (total ~154.9 MB, < proven 205.9 MB) ----
#define H0B    0L
#define H1B    51200000L
#define QB     102400000L
#define KKB    128000000L    // k' (unfinalized, bf16)
#define RMB    153600000L    // fp32 rm [4*50000]
#define WBFB   154400000L    // bf16 GLU weights: layer0 [256][128], layer1 at +65536B
#define V2F0B  154531072L    // fp32 v2x layer0 [4][64][128]
#define V2F1B  154662144L    // fp32 v2x layer1
#define KSB    154793216L    // fp32 ksum [4][64]
#define GMB    154794240L    // 4 uints
#define W12B   154795264L    // bf16: W1 [32][96], W2 [32][96], proj [64][32], W_regT [16][256]
#define V2TB   154819840L    // bf16 v2x^T+ksum [4][144][64]
#define NZERO  65796         // words zeroed at V2F0B (v2x0+v2x1+ksum+gmax)

typedef short short8_t __attribute__((ext_vector_type(8)));
typedef float f32x4 __attribute__((ext_vector_type(4)));

__device__ __forceinline__ unsigned short f2bf(float f){
  unsigned u = __float_as_uint(f);
  return (unsigned short)((u + 0x7FFFu + ((u>>16)&1u)) >> 16);
}
__device__ __forceinline__ float bf2f(unsigned short s){
  return __uint_as_float(((unsigned)s)<<16);
}
__device__ __forceinline__ unsigned pk2(float a, float b){
  return (unsigned)f2bf(a) | ((unsigned)f2bf(b)<<16);
}
__device__ __forceinline__ uint4 pk8(const float* f){
  uint4 o; o.x=pk2(f[0],f[1]); o.y=pk2(f[2],f[3]);
  o.z=pk2(f[4],f[5]); o.w=pk2(f[6],f[7]); return o;
}
__device__ __forceinline__ void up8(uint4 v, float* f){
  f[0]=bf2f((unsigned short)(v.x&0xFFFFu)); f[1]=bf2f((unsigned short)(v.x>>16));
  f[2]=bf2f((unsigned short)(v.y&0xFFFFu)); f[3]=bf2f((unsigned short)(v.y>>16));
  f[4]=bf2f((unsigned short)(v.z&0xFFFFu)); f[5]=bf2f((unsigned short)(v.z>>16));
  f[6]=bf2f((unsigned short)(v.w&0xFFFFu)); f[7]=bf2f((unsigned short)(v.w>>16));
}
__device__ __forceinline__ short8_t relu8(short8_t s){
  short8_t r;
  #pragma unroll
  for (int i=0;i<8;i++){ short v = s[i]; r[i] = (v & (short)0x8000) ? (short)0 : v; }
  return r;
}
__device__ __forceinline__ unsigned encOrd(float f){
  unsigned u = __float_as_uint(f);
  return (u & 0x80000000u) ? ~u : (u | 0x80000000u);
}
__device__ __forceinline__ float decOrd(unsigned u){
  return (u & 0x80000000u) ? __uint_as_float(u & 0x7fffffffu)
                           : __uint_as_float(~u);
}

// ---- zero v2x0+v2x1+ksum+gmax ----
__global__ void k_init(char* __restrict__ wsb){
  int i = blockIdx.x*256 + threadIdx.x;
  if (i < NZERO) ((unsigned*)(wsb + V2F0B))[i] = 0u;
}
// ---- GLU weights -> bf16 [n][k] ----
__global__ void k_wcvt(const float* __restrict__ wi0, const float* __restrict__ wo0,
                       const float* __restrict__ wi1, const float* __restrict__ wo1,
                       char* __restrict__ wsb){
  int idx = blockIdx.x*256 + threadIdx.x;
  if (idx >= 65536) return;
  int l = idx >> 15, r = (idx >> 7) & 255, c = idx & 127;
  const float* src = (l==0) ? ((r<128)? wi0 : wo0) : ((r<128)? wi1 : wo1);
  float v = src[(r&127)*128 + c];
  ((unsigned short*)(wsb + WBFB))[l*32768 + r*128 + c] = f2bf(v);
}
// ---- W1,W2 [32][96], proj [64][32], W_regT [16][256] -> bf16 --------------
__global__ void k_wcvt2(const float* __restrict__ W1, const float* __restrict__ W2,
                        const float* __restrict__ proj, const float* __restrict__ W_reg,
                        char* __restrict__ wsb){
  int i = blockIdx.x*256 + threadIdx.x;          // 12288 total
  if (i >= 12288) return;
  unsigned short* dst = (unsigned short*)(wsb + W12B);
  float v;
  if (i < 3072) v = W1[i];
  else if (i < 6144) v = W2[i-3072];
  else if (i < 8192) v = proj[i-6144];
  else {
    int r = (i-8192) >> 8, c = (i-8192) & 255;
    v = (r < 12) ? W_reg[r*256 + c] : 0.f;
  }
  dst[i] = f2bf(v);
}

// ---------- pass1a: h0 (W_in matmul + embeddings) --------------------------
__global__ __launch_bounds__(256) void k_pass1a(
  const float* __restrict__ x, const float* __restrict__ node_emb,
  const float* __restrict__ time_emb, const float* __restrict__ week_emb,
  const float* __restrict__ W_in, const float* __restrict__ b_in,
  char* __restrict__ wsb)
{
  const int b = blockIdx.y;
  const int n = blockIdx.x*256 + threadIdx.x;
  if (n >= NN) return;
  const long row = (long)b*NN + n;
  float xr[36];
  {
    const float4* xp = (const float4*)(x + row*36);
    #pragma unroll
    for (int i=0;i<9;i++){ float4 t=xp[i]; xr[4*i]=t.x; xr[4*i+1]=t.y; xr[4*i+2]=t.z; xr[4*i+3]=t.w; }
  }
  int tidx = (int)(xr[34]*288.0f); tidx = tidx<0?0:(tidx>287?287:tidx);
  int widx = (int)(xr[35]);        widx = widx<0?0:(widx>6?6:widx);
  uint4* h0q = (uint4*)(wsb + H0B) + row*16;
  float hh[32];
  #pragma unroll 1
  for (int jj=0;jj<8;jj++){
    #pragma unroll
    for (int jl=0;jl<4;jl++){
      const int j = jj*4+jl;
      const float* w = W_in + j*36;
      float a0=0.f,a1=0.f,a2=0.f,a3=0.f;
      #pragma unroll
      for (int i=0;i<36;i+=4){ a0+=xr[i]*w[i]; a1+=xr[i+1]*w[i+1]; a2+=xr[i+2]*w[i+2]; a3+=xr[i+3]*w[i+3]; }
      hh[j] = b_in[j] + ((a0+a1)+(a2+a3));
    }
  }
  #pragma unroll
  for (int c=0;c<4;c++) h0q[c] = pk8(hh + 8*c);
  float xg[96];
  {
    const float4* p0 = (const float4*)(node_emb + (long)n*32);
    const float4* p1 = (const float4*)(time_emb + (long)tidx*32);
    const float4* p2 = (const float4*)(week_emb + (long)widx*32);
    #pragma unroll
    for (int i=0;i<8;i++){ float4 t=p0[i]; xg[4*i]=t.x; xg[4*i+1]=t.y; xg[4*i+2]=t.z; xg[4*i+3]=t.w; }
    #pragma unroll
    for (int i=0;i<8;i++){ float4 t=p1[i]; xg[32+4*i]=t.x; xg[32+4*i+1]=t.y; xg[32+4*i+2]=t.z; xg[32+4*i+3]=t.w; }
    #pragma unroll
    for (int i=0;i<8;i++){ float4 t=p2[i]; xg[64+4*i]=t.x; xg[64+4*i+1]=t.y; xg[64+4*i+2]=t.z; xg[64+4*i+3]=t.w; }
  }
  #pragma unroll
  for (int c=0;c<12;c++) h0q[4+c] = pk8(xg + 8*c);
}

// ---------- pass1b (MFMA): q, k', rm, global key max -----------------------
__global__ __launch_bounds__(256) void k_pass1b(
  const float* __restrict__ b1, const float* __restrict__ b2,
  char* __restrict__ wsb)
{
  __shared__ unsigned short xgt[64][96];
  __shared__ unsigned short dt[2][64][32];
  __shared__ unsigned short ot[64][64];
  __shared__ float wred[4];
  const int b   = blockIdx.y;
  const int tid = threadIdx.x;
  const int lane= tid & 63;
  const int w   = tid >> 6;
  const int c   = lane & 15;
  const int kg  = lane >> 4;
  const long r0blk = (long)blockIdx.x * 64;
  {
    int row = tid >> 2, q3 = tid & 3;
    long gr = r0blk + row;
    uint4 v0={0,0,0,0}, v1=v0, v2=v0;
    if (gr < NN){
      const uint4* src = (const uint4*)(wsb + H0B + ((long)b*NN + gr)*256 + 64 + q3*48);
      v0=src[0]; v1=src[1]; v2=src[2];
    }
    uint4* d = (uint4*)&xgt[row][q3*24];
    d[0]=v0; d[1]=v1; d[2]=v2;
  }
  __syncthreads();
  const unsigned short* w1bf = (const unsigned short*)(wsb + W12B);
  const unsigned short* w2bf = w1bf + 3072;
  const unsigned short* pjbf = w1bf + 6144;
  f32x4 accd[2][2];
  #pragma unroll
  for (int s=0;s<2;s++)
    #pragma unroll
    for (int f=0;f<2;f++) accd[s][f] = (f32x4){0.f,0.f,0.f,0.f};
  #pragma unroll
  for (int ks=0;ks<3;ks++){
    short8_t a = *(const short8_t*)&xgt[w*16 + c][ks*32 + kg*8];
    #pragma unroll
    for (int f=0;f<2;f++){
      short8_t bw1 = *(const short8_t*)(w1bf + (f*16+c)*96 + ks*32 + kg*8);
      accd[0][f] = __builtin_amdgcn_mfma_f32_16x16x32_bf16(a, bw1, accd[0][f], 0,0,0);
      short8_t bw2 = *(const short8_t*)(w2bf + (f*16+c)*96 + ks*32 + kg*8);
      accd[1][f] = __builtin_amdgcn_mfma_f32_16x16x32_bf16(a, bw2, accd[1][f], 0,0,0);
    }
  }
  const float DSC = 0.42044820762685725f;   // 32^-0.25
  float dv[2][2][4];
  #pragma unroll
  for (int f=0;f<2;f++){
    float bb1 = b1[f*16+c], bb2 = b2[f*16+c];
    #pragma unroll
    for (int jj=0;jj<4;jj++){
      dv[0][f][jj] = (accd[0][f][jj] + bb1) * DSC;
      dv[1][f][jj] = (accd[1][f][jj] + bb2) * DSC;
    }
  }
  float dg[2][4];
  #pragma unroll
  for (int s=0;s<2;s++)
    #pragma unroll
    for (int jj=0;jj<4;jj++){
      float t = dv[s][0][jj]*dv[s][0][jj] + dv[s][1][jj]*dv[s][1][jj];
      #pragma unroll
      for (int off=1; off<16; off<<=1) t += __shfl_xor(t, off);
      dg[s][jj] = 0.5f * t;
    }
  #pragma unroll
  for (int s=0;s<2;s++)
    #pragma unroll
    for (int f=0;f<2;f++)
      #pragma unroll
      for (int jj=0;jj<4;jj++)
        dt[s][w*16 + kg*4 + jj][f*16 + c] = f2bf(dv[s][f][jj]);
  __syncthreads();
  f32x4 acc2[2][4];
  #pragma unroll
  for (int s=0;s<2;s++){
    short8_t ad = *(const short8_t*)&dt[s][w*16 + c][kg*8];
    #pragma unroll
    for (int f=0;f<4;f++){
      short8_t bp = *(const short8_t*)(pjbf + (f*16+c)*32 + kg*8);
      acc2[s][f] = __builtin_amdgcn_mfma_f32_16x16x32_bf16(ad, bp, (f32x4){0.f,0.f,0.f,0.f}, 0,0,0);
    }
  }
  float mx[2][4];
  #pragma unroll
  for (int s=0;s<2;s++)
    #pragma unroll
    for (int jj=0;jj<4;jj++){
      float t = fmaxf(fmaxf(acc2[s][0][jj],acc2[s][1][jj]),
                      fmaxf(acc2[s][2][jj],acc2[s][3][jj]));
      #pragma unroll
      for (int off=1; off<16; off<<=1) t = fmaxf(t, __shfl_xor(t, off));
      mx[s][jj] = t;
    }
  #pragma unroll
  for (int f=0;f<4;f++)
    #pragma unroll
    for (int jj=0;jj<4;jj++){
      float qv = 0.125f*(__expf(acc2[0][f][jj] - dg[0][jj] - mx[0][jj]) + 1e-6f);
      ot[w*16 + kg*4 + jj][f*16 + c] = f2bf(qv);
    }
  __syncthreads();
  {
    int row = tid >> 2, q3 = tid & 3;
    long gr = r0blk + row;
    if (gr < NN){
      const uint4* s = (const uint4*)&ot[row][q3*16];
      uint4* dst = (uint4*)((unsigned short*)(wsb + QB) + ((long)b*NN + gr)*64 + q3*16);
      dst[0] = s[0]; dst[1] = s[1];
    }
  }
  __syncthreads();
  float bmax = -3.0e38f;
  #pragma unroll
  for (int f=0;f<4;f++)
    #pragma unroll
    for (int jj=0;jj<4;jj++){
      float kv = __expf(acc2[1][f][jj] - mx[1][jj]);
      ot[w*16 + kg*4 + jj][f*16 + c] = f2bf(kv);
    }
  #pragma unroll
  for (int jj=0;jj<4;jj++){
    long gr = r0blk + w*16 + kg*4 + jj;
    bool val = (gr < NN);
    if (val && c==0)
      ((float*)(wsb + RMB))[(long)b*NN + gr] = mx[1][jj] - dg[1][jj];
    if (val) bmax = fmaxf(bmax, mx[1][jj]);
  }
  #pragma unroll
  for (int off=32; off>0; off>>=1) bmax = fmaxf(bmax, __shfl_xor(bmax, off));
  if (lane==0) wred[w] = bmax;
  __syncthreads();
  {
    int row = tid >> 2, q3 = tid & 3;
    long gr = r0blk + row;
    if (gr < NN){
      const uint4* s = (const uint4*)&ot[row][q3*16];
      uint4* dst = (uint4*)((unsigned short*)(wsb + KKB) + ((long)b*NN + gr)*64 + q3*16);
      dst[0] = s[0]; dst[1] = s[1];
    }
  }
  if (tid==0){
    float m2 = fmaxf(fmaxf(wred[0],wred[1]), fmaxf(wred[2],wred[3]));
    atomicMax((unsigned*)(wsb + GMB) + b, encOrd(m2));
  }
}

// ---------- fused GLU0 + k-finalize + ksum + MFMA reduce -> v2x0 -----------
__global__ __launch_bounds__(256) void k_glured0(
  char* __restrict__ wsb, const unsigned short* __restrict__ wbf,
  const float* __restrict__ bi, const float* __restrict__ bo)
{
  __shared__ unsigned short pool[9216];        // ht[64][136] alias htT[128][72]
  __shared__ unsigned short ktl[64][72];       // finalized k^T [m][n]
  __shared__ float red[256];
  unsigned short (*ht)[136] = (unsigned short(*)[136])pool;
  unsigned short (*htT)[72] = (unsigned short(*)[72])pool;
  const int b = blockIdx.y;
  const int tid = threadIdx.x;
  const int lane = tid & 63;
  const int w = tid >> 6;
  const int c = lane & 15;
  const int kg = lane >> 4;
  const float gm = decOrd(((const unsigned*)(wsb + GMB))[b]);
  const float* rm = (const float*)(wsb + RMB) + (long)b*NN;
  const uint4* kbase = (const uint4*)(wsb + KKB) + (long)b*NN*8;
  const unsigned short* h0g = (const unsigned short*)(wsb + H0B);
  f32x4 racc[8];
  #pragma unroll
  for (int f=0;f<8;f++) racc[f] = (f32x4){0.f,0.f,0.f,0.f};
  float ksacc = 0.f;
  float bi_l[8], bo_l[8];
  #pragma unroll
  for (int f=0;f<8;f++){ bi_l[f] = bi[f*16+c]; bo_l[f] = bo[f*16+c]; }
  #pragma unroll 1
  for (int t=0;t<4;t++){
    const long r0 = (long)blockIdx.x*256 + t*64;
    { // stage h0 tile
      int row = tid>>2, q3 = tid&3;
      long gr = r0 + row;
      uint4 v0={0,0,0,0},v1=v0,v2=v0,v3=v0;
      if (gr < NN){
        const uint4* src = (const uint4*)(h0g + ((long)b*NN + gr)*128 + q3*32);
        v0=src[0]; v1=src[1]; v2=src[2]; v3=src[3];
      }
      uint4* d = (uint4*)&ht[row][q3*32];
      d[0]=v0; d[1]=v1; d[2]=v2; d[3]=v3;
    }
    // stage finalized k^T
    #pragma unroll
    for (int e=0;e<2;e++){
      int f = tid + 256*e;
      int rr = f>>3, cc = f&7;
      long gr = r0 + rr;
      float tv[8];
      if (gr < NN){
        uint4 raw = kbase[gr*8 + cc];
        float scale = __expf(rm[gr] - gm);
        up8(raw, tv);
        #pragma unroll
        for (int i=0;i<8;i++) tv[i] = 0.125f*(tv[i]*scale + 1e-6f);
      } else {
        #pragma unroll
        for (int i=0;i<8;i++) tv[i] = 0.f;
      }
      #pragma unroll
      for (int i=0;i<8;i++) ktl[cc*8+i][rr] = f2bf(tv[i]);
    }
    __syncthreads();
    // GLU0 MFMA
    f32x4 gacc[16];
    #pragma unroll
    for (int f=0;f<16;f++) gacc[f] = (f32x4){0.f,0.f,0.f,0.f};
    #pragma unroll
    for (int ks=0;ks<4;ks++){
      short8_t a = *(const short8_t*)&ht[w*16 + c][ks*32 + kg*8];
      #pragma unroll
      for (int f=0;f<16;f++){
        short8_t bb = *(const short8_t*)(wbf + (f*16 + c)*128 + ks*32 + kg*8);
        gacc[f] = __builtin_amdgcn_mfma_f32_16x16x32_bf16(a, bb, gacc[f], 0, 0, 0);
      }
    }
    float ov[8][4];
    #pragma unroll
    for (int f=0;f<8;f++)
      #pragma unroll
      for (int j=0;j<4;j++){
        float a  = gacc[f][j]   + bi_l[f];
        float cc = gacc[f+8][j] + bo_l[f];
        ov[f][j] = cc / (1.0f + __expf(-a));
      }
    { // ksum partial from ktl
      int m = tid & 63, n0 = (tid>>6)*16;
      #pragma unroll
      for (int n=0;n<16;n++) ksacc += bf2f(ktl[m][n0+n]);
    }
    __syncthreads();   // ht reads done (htT aliases)
    // write v transposed (zero OOB rows)
    #pragma unroll
    for (int f=0;f<8;f++)
      #pragma unroll
      for (int j=0;j<4;j++){
        bool val = (r0 + w*16 + kg*4 + j) < NN;
        htT[f*16 + c][w*16 + kg*4 + j] = val ? f2bf(ov[f][j]) : (unsigned short)0;
      }
    __syncthreads();
    // reduce MFMA: wave w -> out rows m = w*16..+15
    #pragma unroll
    for (int ks=0;ks<2;ks++){
      short8_t a = *(const short8_t*)&ktl[w*16 + c][ks*32 + kg*8];
      #pragma unroll
      for (int f=0;f<8;f++){
        short8_t bb = *(const short8_t*)&htT[f*16 + c][ks*32 + kg*8];
        racc[f] = __builtin_amdgcn_mfma_f32_16x16x32_bf16(a, bb, racc[f], 0, 0, 0);
      }
    }
    __syncthreads();   // loop-end WAR
  }
  float* v2x = (float*)(wsb + V2F0B) + (long)b*8192;
  #pragma unroll
  for (int f=0;f<8;f++)
    #pragma unroll
    for (int j=0;j<4;j++)
      atomicAdd(&v2x[(w*16 + kg*4 + j)*128 + f*16 + c], racc[f][j]);
  red[tid] = ksacc;
  __syncthreads();
  if (tid < 64)
    atomicAdd((float*)(wsb + KSB) + b*64 + tid,
              red[tid]+red[64+tid]+red[128+tid]+red[192+tid]);
}

// ---------- v2t[b][n][m]: n<128: v2x[m][n]; n=128: ksum[m]; n>128: 0 -------
__global__ void k_v2cvt(char* __restrict__ wsb, const float* __restrict__ v2f){
  int idx = blockIdx.x*256 + threadIdx.x;          // 36864
  if (idx >= 36864) return;
  int b = idx / 9216, rem = idx % 9216;
  int n = rem / 64, m = rem % 64;
  const float* ks = (const float*)(wsb + KSB);
  float v = (n < 128) ? v2f[b*8192 + m*128 + n] : ((n==128) ? ks[b*64+m] : 0.f);
  ((unsigned short*)(wsb + V2TB))[b*9216 + n*64 + m] = f2bf(v);
}

// ---------- fused attn0+LN0->h1 + GLU1 + k-finalize + MFMA reduce -> v2x1 --
__global__ __launch_bounds__(256) void k_attnglu1(
  char* __restrict__ wsb, const float* __restrict__ g0,
  const float* __restrict__ bt0, const unsigned short* __restrict__ wbf1,
  const float* __restrict__ bi1, const float* __restrict__ bo1)
{
  __shared__ unsigned short pool[9216];        // ht[64][136] alias htT[128][72]
  __shared__ unsigned short v2s[144*72];
  __shared__ unsigned short ktl[64][72];
  unsigned short (*ht)[136] = (unsigned short(*)[136])pool;
  unsigned short (*htT)[72] = (unsigned short(*)[72])pool;
  const int b = blockIdx.y;
  const int tid = threadIdx.x;
  const int lane = tid & 63;
  const int w = tid >> 6;
  const int c = lane & 15;
  const int kg = lane >> 4;
  const int rrow = tid>>2, rq3 = tid&3;
  const float gm = decOrd(((const unsigned*)(wsb + GMB))[b]);
  const float* rm = (const float*)(wsb + RMB) + (long)b*NN;
  const uint4* kbase = (const uint4*)(wsb + KKB) + (long)b*NN*8;
  // stage v2s once
  {
    const uint4* v2g = (const uint4*)((const unsigned short*)(wsb + V2TB) + b*9216);
    #pragma unroll
    for (int e=0;e<5;e++){
      int j = tid + 256*e;
      if (j < 1152){
        int row = j >> 3, cc = j & 7;
        *(uint4*)&v2s[row*72 + cc*8] = v2g[j];
      }
    }
  }
  f32x4 racc[8];
  #pragma unroll
  for (int f=0;f<8;f++) racc[f] = (f32x4){0.f,0.f,0.f,0.f};
  float bi_l[8], bo_l[8];
  #pragma unroll
  for (int f=0;f<8;f++){ bi_l[f] = bi1[f*16+c]; bo_l[f] = bo1[f*16+c]; }
  #pragma unroll 1
  for (int t=0;t<4;t++){
    const long r0 = (long)blockIdx.x*256 + t*64;
    const long r0w = r0 + w*16;
    const long rgr = r0 + rrow;
    // hoisted loads
    short8_t aq0, aq1;
    if (r0w + c < NN){
      const unsigned short* qrow = (const unsigned short*)(wsb + QB) + ((long)b*NN + r0w + c)*64 + kg*8;
      aq0 = *(const short8_t*)qrow; aq1 = *(const short8_t*)(qrow + 32);
    } else {
      aq0 = (short8_t){0,0,0,0,0,0,0,0}; aq1 = aq0;
    }
    uint4 rh0={0,0,0,0}, rh1={0,0,0,0}, rh2={0,0,0,0}, rh3={0,0,0,0};
    if (rgr < NN){
      const uint4* hs = (const uint4*)((const unsigned short*)(wsb + H0B) + ((long)b*NN + rgr)*128 + rq3*32);
      rh0=hs[0]; rh1=hs[1]; rh2=hs[2]; rh3=hs[3];
    }
    // stage finalized k^T
    #pragma unroll
    for (int e=0;e<2;e++){
      int f = tid + 256*e;
      int rr = f>>3, cc = f&7;
      long gr = r0 + rr;
      float tv[8];
      if (gr < NN){
        uint4 raw = kbase[gr*8 + cc];
        float scale = __expf(rm[gr] - gm);
        up8(raw, tv);
        #pragma unroll
        for (int i=0;i<8;i++) tv[i] = 0.125f*(tv[i]*scale + 1e-6f);
      } else {
        #pragma unroll
        for (int i=0;i<8;i++) tv[i] = 0.f;
      }
      #pragma unroll
      for (int i=0;i<8;i++) ktl[cc*8+i][rr] = f2bf(tv[i]);
    }
    __syncthreads();
    // attn MFMA (B from v2s)
    f32x4 acc[9];
    #pragma unroll
    for (int f=0;f<9;f++) acc[f] = (f32x4){0.f,0.f,0.f,0.f};
    #pragma unroll
    for (int f=0;f<9;f++){
      short8_t b0 = *(const short8_t*)&v2s[(f*16 + c)*72 + kg*8];
      acc[f] = __builtin_amdgcn_mfma_f32_16x16x32_bf16(aq0, b0, acc[f], 0, 0, 0);
      short8_t b1v = *(const short8_t*)&v2s[(f*16 + c)*72 + 32 + kg*8];
      acc[f] = __builtin_amdgcn_mfma_f32_16x16x32_bf16(aq1, b1v, acc[f], 0, 0, 0);
    }
    float inv[4];
    #pragma unroll
    for (int j=0;j<4;j++) inv[j] = 1.0f / __shfl(acc[8][j], (lane & 48));
    #pragma unroll
    for (int f=0;f<8;f++)
      #pragma unroll
      for (int j=0;j<4;j++)
        ht[w*16 + kg*4 + j][f*16 + c] = f2bf(acc[f][j]*inv[j]);
    __syncthreads();
    // row-owner: residual(h0 regs) + LN0 -> h1 (global + ht)
    {
      float tv[32];
      {
        const uint4* os = (const uint4*)&ht[rrow][rq3*32];
        uint4 o0=os[0],o1=os[1],o2=os[2],o3=os[3];
        up8(o0,tv); up8(o1,tv+8); up8(o2,tv+16); up8(o3,tv+24);
      }
      {
        float hv[32];
        up8(rh0,hv); up8(rh1,hv+8); up8(rh2,hv+16); up8(rh3,hv+24);
        #pragma unroll
        for (int i=0;i<32;i++) tv[i] += hv[i];
      }
      float s = 0.f;
      #pragma unroll
      for (int i=0;i<32;i++) s += tv[i];
      s += __shfl_xor(s, 1); s += __shfl_xor(s, 2);
      float mu = s * (1.0f/128.0f);
      float vv = 0.f;
      #pragma unroll
      for (int i=0;i<32;i++){ float e = tv[i]-mu; vv += e*e; }
      vv += __shfl_xor(vv, 1); vv += __shfl_xor(vv, 2);
      float rs = rsqrtf(vv * (1.0f/128.0f) + 1e-5f);
      const float4* gp = (const float4*)(g0 + rq3*32);
      const float4* bp = (const float4*)(bt0 + rq3*32);
      float h1v[32];
      #pragma unroll
      for (int i8=0;i8<8;i8++){
        float4 g4 = gp[i8], b4 = bp[i8];
        h1v[i8*4  ] = (tv[i8*4  ]-mu)*rs*g4.x + b4.x;
        h1v[i8*4+1] = (tv[i8*4+1]-mu)*rs*g4.y + b4.y;
        h1v[i8*4+2] = (tv[i8*4+2]-mu)*rs*g4.z + b4.z;
        h1v[i8*4+3] = (tv[i8*4+3]-mu)*rs*g4.w + b4.w;
      }
      uint4 p0=pk8(h1v), p1=pk8(h1v+8), p2=pk8(h1v+16), p3=pk8(h1v+24);
      if (rgr < NN){
        uint4* dst = (uint4*)((unsigned short*)(wsb + H1B) + ((long)b*NN + rgr)*128 + rq3*32);
        dst[0]=p0; dst[1]=p1; dst[2]=p2; dst[3]=p3;
      }
      uint4* d = (uint4*)&ht[rrow][rq3*32];
      d[0]=p0; d[1]=p1; d[2]=p2; d[3]=p3;
    }
    __syncthreads();
    // GLU1 MFMA from ht(h1)
    f32x4 gacc[16];
    #pragma unroll
    for (int f=0;f<16;f++) gacc[f] = (f32x4){0.f,0.f,0.f,0.f};
    #pragma unroll
    for (int ks=0;ks<4;ks++){
      short8_t a = *(const short8_t*)&ht[w*16 + c][ks*32 + kg*8];
      #pragma unroll
      for (int f=0;f<16;f++){
        short8_t bb = *(const short8_t*)(wbf1 + (f*16 + c)*128 + ks*32 + kg*8);
        gacc[f] = __builtin_amdgcn_mfma_f32_16x16x32_bf16(a, bb, gacc[f], 0, 0, 0);
      }
    }
    float ov[8][4];
    #pragma unroll
    for (int f=0;f<8;f++)
      #pragma unroll
      for (int j=0;j<4;j++){
        float a  = gacc[f][j]   + bi_l[f];
        float cc = gacc[f+8][j] + bo_l[f];
        ov[f][j] = cc / (1.0f + __expf(-a));
      }
    __syncthreads();   // ht reads done (htT aliases)
    // write v1 transposed (zero OOB rows -- blocks NaN propagation)
    #pragma unroll
    for (int f=0;f<8;f++)
      #pragma unroll
      for (int j=0;j<4;j++){
        bool val = (r0 + w*16 + kg*4 + j) < NN;
        htT[f*16 + c][w*16 + kg*4 + j] = val ? f2bf(ov[f][j]) : (unsigned short)0;
      }
    __syncthreads();
    // reduce MFMA
    #pragma unroll
    for (int ks=0;ks<2;ks++){
      short8_t a = *(const short8_t*)&ktl[w*16 + c][ks*32 + kg*8];
      #pragma unroll
      for (int f=0;f<8;f++){
        short8_t bb = *(const short8_t*)&htT[f*16 + c][ks*32 + kg*8];
        racc[f] = __builtin_amdgcn_mfma_f32_16x16x32_bf16(a, bb, racc[f], 0, 0, 0);
      }
    }
    __syncthreads();   // loop-end WAR
  }
  float* v2x = (float*)(wsb + V2F1B) + (long)b*8192;
  #pragma unroll
  for (int f=0;f<8;f++)
    #pragma unroll
    for (int j=0;j<4;j++)
      atomicAdd(&v2x[(w*16 + kg*4 + j)*128 + f*16 + c], racc[f][j]);
}

// ---------- attn1 + residual(h1) + LN1 + MFMA regression head --------------
__global__ __launch_bounds__(256) void k_attnhead(
  char* __restrict__ wsb, const float* __restrict__ g1,
  const float* __restrict__ bt1, const float* __restrict__ b_reg,
  float* __restrict__ out)
{
  __shared__ unsigned short ht[64][136];
  __shared__ unsigned short v2s[144*72];    // reused as h0 tile [64][136]
  const int b = blockIdx.y;
  const int tid = threadIdx.x;
  const int lane = tid & 63;
  const int w  = tid >> 6;
  const int c  = lane & 15;
  const int kg = lane >> 4;
  const long r0blk = (long)blockIdx.x*64;
  const long r0w = r0blk + w*16;
  const int rrow = tid>>2, rq3 = tid&3;
  const long rgr = r0blk + rrow;
  short8_t aq0, aq1;
  if (r0w + c < NN){
    const unsigned short* qrow = (const unsigned short*)(wsb + QB) + ((long)b*NN + r0w + c)*64 + kg*8;
    aq0 = *(const short8_t*)qrow; aq1 = *(const short8_t*)(qrow + 32);
  } else {
    aq0 = (short8_t){0,0,0,0,0,0,0,0}; aq1 = aq0;
  }
  uint4 rh0={0,0,0,0}, rh1={0,0,0,0}, rh2={0,0,0,0}, rh3={0,0,0,0};
  uint4 ah0={0,0,0,0}, ah1={0,0,0,0}, ah2={0,0,0,0}, ah3={0,0,0,0};
  if (rgr < NN){
    const uint4* hs = (const uint4*)((const unsigned short*)(wsb + H1B) + ((long)b*NN + rgr)*128 + rq3*32);
    rh0=hs[0]; rh1=hs[1]; rh2=hs[2]; rh3=hs[3];
    const uint4* h0s = (const uint4*)((const unsigned short*)(wsb + H0B) + ((long)b*NN + rgr)*128 + rq3*32);
    ah0=h0s[0]; ah1=h0s[1]; ah2=h0s[2]; ah3=h0s[3];
  }
  {
    const uint4* v2g = (const uint4*)((const unsigned short*)(wsb + V2TB) + b*9216);
    #pragma unroll
    for (int e=0;e<5;e++){
      int j = tid + 256*e;
      if (j < 1152){
        int row = j >> 3, cc = j & 7;
        *(uint4*)&v2s[row*72 + cc*8] = v2g[j];
      }
    }
  }
  __syncthreads();
  f32x4 acc[9];
  #pragma unroll
  for (int f=0;f<9;f++) acc[f] = (f32x4){0.f,0.f,0.f,0.f};
  #pragma unroll
  for (int f=0;f<9;f++){
    short8_t b0 = *(const short8_t*)&v2s[(f*16 + c)*72 + kg*8];
    acc[f] = __builtin_amdgcn_mfma_f32_16x16x32_bf16(aq0, b0, acc[f], 0, 0, 0);
    short8_t b1v = *(const short8_t*)&v2s[(f*16 + c)*72 + 32 + kg*8];
    acc[f] = __builtin_amdgcn_mfma_f32_16x16x32_bf16(aq1, b1v, acc[f], 0, 0, 0);
  }
  float inv[4];
  #pragma unroll
  for (int j=0;j<4;j++) inv[j] = 1.0f / __shfl(acc[8][j], (lane & 48));
  #pragma unroll
  for (int f=0;f<8;f++)
    #pragma unroll
    for (int j=0;j<4;j++)
      ht[w*16 + kg*4 + j][f*16 + c] = f2bf(acc[f][j]*inv[j]);
  __syncthreads();   // v2s reads done -> reuse as h0 tile
  {
    unsigned short* h0t = v2s;
    uint4* hd = (uint4*)&h0t[rrow*136 + rq3*32];
    hd[0]=ah0; hd[1]=ah1; hd[2]=ah2; hd[3]=ah3;
    float tv[32];
    {
      const uint4* os = (const uint4*)&ht[rrow][rq3*32];
      uint4 o0=os[0],o1=os[1],o2=os[2],o3=os[3];
      up8(o0,tv); up8(o1,tv+8); up8(o2,tv+16); up8(o3,tv+24);
    }
    {
      float hv[32];
      up8(rh0,hv); up8(rh1,hv+8); up8(rh2,hv+16); up8(rh3,hv+24);
      #pragma unroll
      for (int i=0;i<32;i++) tv[i] += hv[i];
    }
    float s = 0.f;
    #pragma unroll
    for (int i=0;i<32;i++) s += tv[i];
    s += __shfl_xor(s, 1); s += __shfl_xor(s, 2);
    float mu = s * (1.0f/128.0f);
    float vv = 0.f;
    #pragma unroll
    for (int i=0;i<32;i++){ float e = tv[i]-mu; vv += e*e; }
    vv += __shfl_xor(vv, 1); vv += __shfl_xor(vv, 2);
    float rs = rsqrtf(vv * (1.0f/128.0f) + 1e-5f);
    const float4* gp = (const float4*)(g1 + rq3*32);
    const float4* bp = (const float4*)(bt1 + rq3*32);
    float h2v[32];
    #pragma unroll
    for (int i8=0;i8<8;i8++){
      float4 g4 = gp[i8], b4 = bp[i8];
      h2v[i8*4  ] = fmaxf((tv[i8*4  ]-mu)*rs*g4.x + b4.x, 0.f);
      h2v[i8*4+1] = fmaxf((tv[i8*4+1]-mu)*rs*g4.y + b4.y, 0.f);
      h2v[i8*4+2] = fmaxf((tv[i8*4+2]-mu)*rs*g4.z + b4.z, 0.f);
      h2v[i8*4+3] = fmaxf((tv[i8*4+3]-mu)*rs*g4.w + b4.w, 0.f);
    }
    uint4 p0=pk8(h2v), p1=pk8(h2v+8), p2=pk8(h2v+16), p3=pk8(h2v+24);
    uint4* d = (uint4*)&ht[rrow][rq3*32];
    d[0]=p0; d[1]=p1; d[2]=p2; d[3]=p3;
  }
  __syncthreads();
  const unsigned short* wregT = (const unsigned short*)(wsb + W12B) + 8192;
  const unsigned short* h0t = v2s;
  f32x4 hacc = (f32x4){0.f,0.f,0.f,0.f};
  #pragma unroll
  for (int ks=0;ks<8;ks++){
    short8_t a;
    if (ks < 4)
      a = relu8(*(const short8_t*)&h0t[(w*16 + c)*136 + ks*32 + kg*8]);
    else
      a = *(const short8_t*)&ht[w*16 + c][(ks-4)*32 + kg*8];
    short8_t bb = *(const short8_t*)(wregT + c*256 + ks*32 + kg*8);
    hacc = __builtin_amdgcn_mfma_f32_16x16x32_bf16(a, bb, hacc, 0, 0, 0);
  }
  if (c < 12){
    float br = b_reg[c];
    #pragma unroll
    for (int j=0;j<4;j++){
      long gr = r0w + kg*4 + j;
      if (gr < NN)
        out[((long)b*12 + c)*NN + gr] = hacc[j] + br;
    }
  }
}

extern "C" void kernel_launch(void* const* d_in, const int* in_sizes, int n_in,
                              void* d_out, int out_size, void* d_ws, size_t ws_size,
                              hipStream_t stream)
{
  const float* x        = (const float*)d_in[0];
  const float* node_emb = (const float*)d_in[1];
  const float* time_emb = (const float*)d_in[2];
  const float* week_emb = (const float*)d_in[3];
  const float* W_in     = (const float*)d_in[4];
  const float* b_in     = (const float*)d_in[5];
  const float* W1       = (const float*)d_in[6];
  const float* b1       = (const float*)d_in[7];
  const float* W2       = (const float*)d_in[8];
  const float* b2       = (const float*)d_in[9];
  const float* W_reg    = (const float*)d_in[10];
  const float* b_reg    = (const float*)d_in[11];
  const float* proj     = (const float*)d_in[12];
  const float* fc_in0_w = (const float*)d_in[13];
  const float* fc_in0_b = (const float*)d_in[14];
  const float* fc_out0_w= (const float*)d_in[15];
  const float* fc_out0_b= (const float*)d_in[16];
  const float* ln0_g    = (const float*)d_in[17];
  const float* ln0_b    = (const float*)d_in[18];
  const float* fc_in1_w = (const float*)d_in[19];
  const float* fc_in1_b = (const float*)d_in[20];
  const float* fc_out1_w= (const float*)d_in[21];
  const float* fc_out1_b= (const float*)d_in[22];
  const float* ln1_g    = (const float*)d_in[23];
  const float* ln1_b    = (const float*)d_in[24];
  char* wsb  = (char*)d_ws;
  float* out = (float*)d_out;

  dim3 rowgrid((NN+255)/256, NB);     // (196, 4)
  dim3 atngrid(782, NB);              // 782*64 = 50048 >= NN
  dim3 fgrid(196, NB);                // 196*256 = 50176 >= NN, 4 tiles/block

  k_init  <<<258, 256, 0, stream>>>(wsb);
  k_wcvt  <<<256, 256, 0, stream>>>(fc_in0_w, fc_out0_w, fc_in1_w, fc_out1_w, wsb);
  k_wcvt2 <<<48, 256, 0, stream>>>(W1, W2, proj, W_reg, wsb);
  k_pass1a<<<rowgrid, 256, 0, stream>>>(x, node_emb, time_emb, week_emb,
                                        W_in, b_in, wsb);
  k_pass1b<<<atngrid, 256, 0, stream>>>(b1, b2, wsb);
  k_glured0<<<fgrid, 256, 0, stream>>>(wsb, (const unsigned short*)(wsb + WBFB),
                                       fc_in0_b, fc_out0_b);
  k_v2cvt <<<144, 256, 0, stream>>>(wsb, (const float*)(wsb + V2F0B));
  k_attnglu1<<<fgrid, 256, 0, stream>>>(wsb, ln0_g, ln0_b,
                                        (const unsigned short*)(wsb + WBFB) + 32768,
                                        fc_in1_b, fc_out1_b);
  k_v2cvt <<<144, 256, 0, stream>>>(wsb, (const float*)(wsb + V2F1B));
  k_attnhead<<<atngrid, 256, 0, stream>>>(wsb, ln1_g, ln1_b, b_reg, out);
}